// Round 5
// baseline (626.245 us; speedup 1.0000x reference)
//
#include <hip/hip_runtime.h>
#include <hip/hip_bf16.h>
#include <math.h>

#define NTOK 8192
#define DM   1024
#define NE   16
#define HD   4096
#define CAP  640

typedef float f32x4 __attribute__((ext_vector_type(4)));
typedef _Float16 f16x8 __attribute__((ext_vector_type(8)));
typedef _Float16 f16x4 __attribute__((ext_vector_type(4)));

__device__ __forceinline__ void gload16(const void* g, void* l) {
  __builtin_amdgcn_global_load_lds(
      (const __attribute__((address_space(1))) unsigned int*)g,
      (__attribute__((address_space(3))) unsigned int*)l, 16, 0, 0);
}

// ---------------- router: logits + softmax + col partials (one wave/token) ----------------
__global__ __launch_bounds__(256) void k_router(const float* __restrict__ x,
                                                const float* __restrict__ Wr,
                                                float* __restrict__ probs,
                                                float* __restrict__ pout) {
  int wave = threadIdx.x >> 6, lane = threadIdx.x & 63;
  int tok = blockIdx.x * 4 + wave;
  const float* xr = x + (size_t)tok * DM;
  float acc[NE];
#pragma unroll
  for (int e = 0; e < NE; ++e) acc[e] = 0.f;
  for (int d = lane; d < DM; d += 64) {
    float xv = xr[d];
    const float* w = Wr + (size_t)d * NE;
#pragma unroll
    for (int e = 0; e < NE; ++e) acc[e] = fmaf(xv, w[e], acc[e]);
  }
#pragma unroll
  for (int off = 32; off >= 1; off >>= 1) {
#pragma unroll
    for (int e = 0; e < NE; ++e) acc[e] += __shfl_xor(acc[e], off, 64);
  }
  float m = acc[0];
#pragma unroll
  for (int e = 1; e < NE; ++e) m = fmaxf(m, acc[e]);
  float s = 0.f;
#pragma unroll
  for (int e = 0; e < NE; ++e) { acc[e] = expf(acc[e] - m); s += acc[e]; }
  float inv = 1.0f / s;
#pragma unroll
  for (int e = 0; e < NE; ++e) acc[e] *= inv;
  if (lane < NE) probs[(size_t)tok * NE + lane] = acc[lane];
  __shared__ float wsum[4][NE];
  if (lane == 0) {
#pragma unroll
    for (int e = 0; e < NE; ++e) wsum[wave][e] = acc[e];
  }
  __syncthreads();
  if (threadIdx.x < NE)
    pout[blockIdx.x * NE + threadIdx.x] =
        wsum[0][threadIdx.x] + wsum[1][threadIdx.x] + wsum[2][threadIdx.x] + wsum[3][threadIdx.x];
}

// ------------- fused sinkhorn step: col-normalize, row-normalize, emit col partials -------------
__global__ __launch_bounds__(256) void k_sink(float* __restrict__ probs,
                                              const float* __restrict__ pin,
                                              float* __restrict__ pout) {
  __shared__ float csinv[NE];
  int tid = threadIdx.x;
  if (tid < NE) {
    float s = 0.f;
#pragma unroll
    for (int b = 0; b < 32; ++b) s += pin[b * NE + tid];
    csinv[tid] = 512.0f / s;
  }
  __syncthreads();
  int tok = blockIdx.x * 256 + tid;
  float* row = probs + (size_t)tok * NE;
  float p[NE]; float rs = 0.f;
#pragma unroll
  for (int e = 0; e < NE; ++e) { p[e] = row[e] * csinv[e]; rs += p[e]; }
  float rinv = 1.0f / rs;
#pragma unroll
  for (int e = 0; e < NE; ++e) { p[e] *= rinv; row[e] = p[e]; }
#pragma unroll
  for (int off = 32; off >= 1; off >>= 1) {
#pragma unroll
    for (int e = 0; e < NE; ++e) p[e] += __shfl_xor(p[e], off, 64);
  }
  __shared__ float wsum[4][NE];
  int lane = tid & 63, wave = tid >> 6;
  if (lane == 0) {
#pragma unroll
    for (int e = 0; e < NE; ++e) wsum[wave][e] = p[e];
  }
  __syncthreads();
  if (tid < NE)
    pout[blockIdx.x * NE + tid] =
        wsum[0][tid] + wsum[1][tid] + wsum[2][tid] + wsum[3][tid];
}

// ------------- final sinkhorn col-normalize fused with top-2 + weight renorm -------------
__global__ __launch_bounds__(256) void k_sink3(const float* __restrict__ probs,
                                               const float* __restrict__ pin,
                                               int* __restrict__ eidx,
                                               float* __restrict__ ew) {
  __shared__ float csinv[NE];
  int tid = threadIdx.x;
  if (tid < NE) {
    float s = 0.f;
#pragma unroll
    for (int b = 0; b < 32; ++b) s += pin[b * NE + tid];
    csinv[tid] = 512.0f / s;
  }
  __syncthreads();
  int tok = blockIdx.x * 256 + tid;
  const float* row = probs + (size_t)tok * NE;
  float v0 = -1e30f, v1 = -1e30f; int e0 = 0, e1 = 0;
#pragma unroll
  for (int e = 0; e < NE; ++e) {
    float v = row[e] * csinv[e];
    if (v > v0) { v1 = v0; e1 = e0; v0 = v; e0 = e; }
    else if (v > v1) { v1 = v; e1 = e; }
  }
  float s = v0 + v1;
  eidx[tok * 2] = e0; eidx[tok * 2 + 1] = e1;
  ew[tok * 2] = v0 / s; ew[tok * 2 + 1] = v1 / s;
}

// ------------- sequential (t,k)-order slot allocation: one block per expert -------------
__global__ __launch_bounds__(256) void k_scan(const int* __restrict__ eidx,
                                              const float* __restrict__ ew,
                                              int* __restrict__ slot_tok,
                                              float* __restrict__ slot_w,
                                              int* __restrict__ counts) {
  int e = blockIdx.x;
  int tid = threadIdx.x, lane = tid & 63, wave = tid >> 6;
  __shared__ int wtot[4];
  int running = 0;
  for (int base = 0; base < NTOK * 2; base += 256) {
    int i = base + tid;
    int match = (eidx[i] == e) ? 1 : 0;
    unsigned long long mb = __ballot(match);
    if (lane == 0) wtot[wave] = __popcll(mb);
    __syncthreads();
    int pre = 0;
    for (int w = 0; w < wave; ++w) pre += wtot[w];
    int tot = wtot[0] + wtot[1] + wtot[2] + wtot[3];
    if (match) {
      int pos = running + pre + __popcll(mb & ((1ull << lane) - 1ull));
      if (pos < CAP) {
        slot_tok[e * CAP + pos] = i >> 1;
        slot_w[e * CAP + pos] = ew[i];
      }
    }
    running += tot;
    __syncthreads();
  }
  if (tid == 0) counts[e] = running;
}

__global__ void k_aux(const int* __restrict__ counts, float* __restrict__ aux) {
  int s = 0;
#pragma unroll
  for (int e = 0; e < NE; ++e) s += min(counts[e], CAP);
  *aux = 0.01f * (float)s / (float)NTOK;
}

// ------------- gather expert inputs to fp16 (zero-fill unused slots) -------------
__global__ __launch_bounds__(256) void k_gather(const float* __restrict__ x,
                                                const int* __restrict__ slot_tok,
                                                _Float16* __restrict__ xg) {
  int row = blockIdx.x;
  int tok = slot_tok[row];
  int t = threadIdx.x;
  f16x4 h;
  if (tok >= 0) {
    float4 v = *(const float4*)(x + (size_t)tok * DM + t * 4);
    h[0] = (_Float16)v.x; h[1] = (_Float16)v.y; h[2] = (_Float16)v.z; h[3] = (_Float16)v.w;
  } else {
    h[0] = (_Float16)0.f; h[1] = (_Float16)0.f; h[2] = (_Float16)0.f; h[3] = (_Float16)0.f;
  }
  *(f16x4*)(xg + (size_t)row * DM + t * 4) = h;
}

// ------------- transpose+convert: W[e][K][N] fp32 -> WT[e][N][K] fp16 -------------
__global__ __launch_bounds__(256) void k_transpose(const float* __restrict__ W,
                                                   _Float16* __restrict__ WT,
                                                   int K, int N) {
  __shared__ float tile[64][65];
  int e = blockIdx.z;
  int n0 = blockIdx.x * 64, k0 = blockIdx.y * 64;
  const float* src = W + ((size_t)e * K + k0) * N + n0;
  int t = threadIdx.x;
  int kr = t >> 4, nc = (t & 15) * 4;
#pragma unroll
  for (int r = 0; r < 4; ++r) {
    int row = r * 16 + kr;
    float4 v = *(const float4*)(src + (size_t)row * N + nc);
    tile[row][nc + 0] = v.x; tile[row][nc + 1] = v.y;
    tile[row][nc + 2] = v.z; tile[row][nc + 3] = v.w;
  }
  __syncthreads();
  int nr = t >> 3, kc = (t & 7) * 8;
  size_t dstbase = ((size_t)e * N + n0) * (size_t)K + k0;
#pragma unroll
  for (int r = 0; r < 2; ++r) {
    int n = r * 32 + nr;
    f16x8 h;
#pragma unroll
    for (int j = 0; j < 8; ++j) h[j] = (_Float16)tile[kc + j][n];
    *(f16x8*)(WT + dstbase + (size_t)n * K + kc) = h;
  }
}

// ==================== fp16 MFMA GEMMs: 256x256, BK=64, 8 waves, 8-phase + counted vmcnt ====================
// LDS: 2 buffers x (A 256x64 + B 256x64) fp16 = 131072 B. 16B chunks XOR-swizzled (c ^= row&7);
// global_load_lds writes linearly -> GLOBAL source address pre-swizzled.
// Per K-tile: 4 phases, each {2 gload16 of next tile || ds_read quadrant -> barrier -> 16 MFMA (setprio) -> barrier};
// single counted vmcnt(2) per K-tile (never vmcnt(0) in steady state).

#define PREP_STAGE(AB, LDA, ALIM, BB, LDB)                                   \
  const _Float16* gp[8]; int lo[8];                                          \
  _Pragma("unroll")                                                          \
  for (int j = 0; j < 8; ++j) {                                              \
    int arr = j & 1, part = j >> 1;                                          \
    int ci = part * 512 + w * 64 + lane;                                     \
    int row = ci >> 3, cs = (ci & 7) ^ (row & 7);                            \
    if (arr == 0) { int rc = row < (ALIM) ? row : (ALIM);                    \
                    gp[j] = (AB) + (size_t)rc * (LDA) + cs * 8; }            \
    else          { gp[j] = (BB) + (size_t)row * (LDB) + cs * 8; }           \
    lo[j] = arr * 16384 + (part * 512 + w * 64) * 8;                         \
  }

#define LOAD_B(Bs, ks)                                                       \
  _Pragma("unroll") for (int n = 0; n < 4; ++n) {                            \
    int row = wc * 64 + n * 16 + lr;                                         \
    bf[n] = *(const f16x8*)((Bs) + row * 64 + ((((ks)*4 + kg) ^ (row & 7)) << 3)); \
  }
#define LOAD_A(As, ks, mh)                                                   \
  _Pragma("unroll") for (int mm = 0; mm < 4; ++mm) {                         \
    int row = wr * 128 + ((mh)*4 + mm) * 16 + lr;                            \
    af[mm] = *(const f16x8*)((As) + row * 64 + ((((ks)*4 + kg) ^ (row & 7)) << 3)); \
  }
#define MFMA16(mh)                                                           \
  __builtin_amdgcn_s_setprio(1);                                             \
  _Pragma("unroll") for (int mm = 0; mm < 4; ++mm)                           \
    _Pragma("unroll") for (int n = 0; n < 4; ++n)                            \
      acc[(mh)*4 + mm][n] = __builtin_amdgcn_mfma_f32_16x16x32_f16(af[mm], bf[n], acc[(mh)*4 + mm][n], 0, 0, 0); \
  __builtin_amdgcn_s_setprio(0);

#define BAR()  __builtin_amdgcn_s_barrier(); __builtin_amdgcn_sched_barrier(0)

#define K_LOOP(NT, KBASE)                                                    \
  {                                                                          \
    _Pragma("unroll")                                                        \
    for (int j = 0; j < 8; ++j) gload16(gp[j] + (KBASE), sm + lo[j]);        \
    for (int t = 0; t < (NT); ++t) {                                         \
      const _Float16* As = sm + (t & 1) * 32768;                             \
      const _Float16* Bs = As + 16384;                                       \
      _Float16* nxt = sm + ((t + 1) & 1) * 32768;                            \
      f16x8 af[4], bf[4];                                                    \
      int kn = (KBASE) + (t + 1) * 64;                                       \
      bool pf = (t + 1) < (NT);                                              \
      /* phase 0: prefetch j0,j1; counted drain of tile t; quadrant (ks0,mh0) */ \
      if (pf) { gload16(gp[0] + kn, nxt + lo[0]); gload16(gp[1] + kn, nxt + lo[1]); \
                asm volatile("s_waitcnt vmcnt(2)" ::: "memory"); }           \
      else    { asm volatile("s_waitcnt vmcnt(0)" ::: "memory"); }           \
      BAR();                                                                 \
      LOAD_B(Bs, 0); LOAD_A(As, 0, 0);                                       \
      MFMA16(0);                                                             \
      BAR();                                                                 \
      /* phase 1: (ks0,mh1), reuse bf */                                     \
      LOAD_A(As, 0, 1);                                                      \
      if (pf) { gload16(gp[2] + kn, nxt + lo[2]); gload16(gp[3] + kn, nxt + lo[3]); } \
      BAR();                                                                 \
      MFMA16(1);                                                             \
      BAR();                                                                 \
      /* phase 2: (ks1,mh0) */                                               \
      LOAD_B(Bs, 1); LOAD_A(As, 1, 0);                                       \
      if (pf) { gload16(gp[4] + kn, nxt + lo[4]); gload16(gp[5] + kn, nxt + lo[5]); } \
      BAR();                                                                 \
      MFMA16(0);                                                             \
      BAR();                                                                 \
      /* phase 3: (ks1,mh1), reuse bf */                                     \
      LOAD_A(As, 1, 1);                                                      \
      if (pf) { gload16(gp[6] + kn, nxt + lo[6]); gload16(gp[7] + kn, nxt + lo[7]); } \
      BAR();                                                                 \
      MFMA16(1);                                                             \
      BAR();                                                                 \
    }                                                                        \
  }

// ---- GEMM1: h = gelu(xg @ W1T^T + b1); grid 3m x 16n x 16e = 768 blocks ----
__global__ __launch_bounds__(512, 2) void k_mm1(const _Float16* __restrict__ xg,
                                                const _Float16* __restrict__ W1T,
                                                const float* __restrict__ b1,
                                                _Float16* __restrict__ hbuf) {
  extern __shared__ _Float16 sm[];
  int bid = blockIdx.x;
  int L = (bid & 7) * 96 + (bid >> 3);
  int my = L % 3;
  int nx = (L / 3) & 15;
  int e  = L / 48;
  int m0 = my * 256, n0 = nx * 256;
  const _Float16* Ab = xg  + ((size_t)e * CAP + m0) * DM;
  const _Float16* Bb = W1T + ((size_t)e * HD  + n0) * DM;
  int alim = CAP - 1 - m0;

  int tid = threadIdx.x, lane = tid & 63, w = tid >> 6;
  int wr = w >> 2, wc = w & 3;
  int lr = lane & 15, kg = lane >> 4, lq = kg;

  f32x4 acc[8][4];
#pragma unroll
  for (int m = 0; m < 8; ++m)
#pragma unroll
    for (int n = 0; n < 4; ++n) acc[m][n] = (f32x4){0.f, 0.f, 0.f, 0.f};

  PREP_STAGE(Ab, DM, alim, Bb, DM);
  K_LOOP(16, 0);

  // epilogue: bias + exact GELU -> fp16, bounce via LDS (256x256) for coalesced stores
  __syncthreads();
  _Float16* Cb = sm;
  float bias[4];
#pragma unroll
  for (int n = 0; n < 4; ++n)
    bias[n] = b1[(size_t)e * HD + n0 + wc * 64 + n * 16 + lr];
#pragma unroll
  for (int m = 0; m < 8; ++m) {
#pragma unroll
    for (int n = 0; n < 4; ++n) {
#pragma unroll
      for (int r = 0; r < 4; ++r) {
        int row = wr * 128 + m * 16 + lq * 4 + r;
        int col = wc * 64 + n * 16 + lr;
        float v = acc[m][n][r] + bias[n];
        v = 0.5f * v * (1.0f + erff(v * 0.70710678118654752f));
        Cb[row * 256 + (col ^ (((row >> 2) & 3) << 4))] = (_Float16)v;
      }
    }
  }
  __syncthreads();
  int r8 = tid >> 5, c8 = (tid & 31) * 8;
#pragma unroll
  for (int p = 0; p < 16; ++p) {
    int row = p * 16 + r8;
    if (m0 + row < CAP) {
      int colx = c8 ^ (((row >> 2) & 3) << 4);
      f16x8 v = *(const f16x8*)(Cb + row * 256 + colx);
      *(f16x8*)(hbuf + ((size_t)e * CAP + m0 + row) * HD + n0 + c8) = v;
    }
  }
}

// ---- GEMM2: y[tok] += w*(h @ W2T^T + b2); K split 4; grid 3m x 4n x 4ks x 16e = 768 ----
__global__ __launch_bounds__(512, 2) void k_mm2(const _Float16* __restrict__ hbuf,
                                                const _Float16* __restrict__ W2T,
                                                const float* __restrict__ b2,
                                                const int* __restrict__ slot_tok,
                                                const float* __restrict__ slot_w,
                                                float* __restrict__ y) {
  extern __shared__ _Float16 sm[];
  int bid = blockIdx.x;
  int L = (bid & 7) * 96 + (bid >> 3);
  int my = L % 3;
  int ks4 = (L / 3) & 3;
  int nx  = (L / 12) & 3;
  int e   = L / 48;
  int m0 = my * 256, n0 = nx * 256, kbase = ks4 * 1024;
  const _Float16* Ab = hbuf + ((size_t)e * CAP + m0) * HD;
  const _Float16* Bb = W2T  + ((size_t)e * DM  + n0) * HD;
  int alim = CAP - 1 - m0;

  int tid = threadIdx.x, lane = tid & 63, w = tid >> 6;
  int wr = w >> 2, wc = w & 3;
  int lr = lane & 15, kg = lane >> 4, lq = kg;

  f32x4 acc[8][4];
#pragma unroll
  for (int m = 0; m < 8; ++m)
#pragma unroll
    for (int n = 0; n < 4; ++n) acc[m][n] = (f32x4){0.f, 0.f, 0.f, 0.f};

  PREP_STAGE(Ab, HD, alim, Bb, HD);
  K_LOOP(16, kbase);

  // epilogue: bias (only ks==0), gate weight, atomic scatter-combine
  float bias[4];
#pragma unroll
  for (int n = 0; n < 4; ++n)
    bias[n] = (ks4 == 0) ? b2[(size_t)e * DM + n0 + wc * 64 + n * 16 + lr] : 0.f;
#pragma unroll
  for (int m = 0; m < 8; ++m) {
#pragma unroll
    for (int r = 0; r < 4; ++r) {
      int rowg = m0 + wr * 128 + m * 16 + lq * 4 + r;
      if (rowg < CAP) {
        int tk = slot_tok[e * CAP + rowg];
        if (tk >= 0) {
          float wgt = slot_w[e * CAP + rowg];
#pragma unroll
          for (int n = 0; n < 4; ++n) {
            int col = n0 + wc * 64 + n * 16 + lr;
            atomicAdd(&y[(size_t)tk * DM + col], wgt * (acc[m][n][r] + bias[n]));
          }
        }
      }
    }
  }
}

extern "C" void kernel_launch(void* const* d_in, const int* in_sizes, int n_in,
                              void* d_out, int out_size, void* d_ws, size_t ws_size,
                              hipStream_t stream) {
  const float* x  = (const float*)d_in[0];
  const float* Wr = (const float*)d_in[1];
  const float* W1 = (const float*)d_in[2];
  const float* b1 = (const float*)d_in[3];
  const float* W2 = (const float*)d_in[4];
  const float* b2 = (const float*)d_in[5];
  float* y = (float*)d_out;
  float* aux = y + (size_t)out_size - 1;

  char* ws = (char*)d_ws;
  float* probs    = (float*)ws; ws += (size_t)NTOK * NE * 4;   // 512 KB
  float* P0       = (float*)ws; ws += 32 * NE * 4;
  float* P1       = (float*)ws; ws += 32 * NE * 4;
  int*   eidx     = (int*)ws;   ws += NTOK * 2 * 4;
  float* ew       = (float*)ws; ws += NTOK * 2 * 4;
  int*   slot_tok = (int*)ws;   ws += NE * CAP * 4;
  float* slot_w   = (float*)ws; ws += NE * CAP * 4;
  int*   counts   = (int*)ws;   ws += 256;
  _Float16* xg    = (_Float16*)ws; ws += (size_t)NE * CAP * DM * 2;   // 20 MB
  _Float16* hbuf  = (_Float16*)ws; ws += (size_t)NE * CAP * HD * 2;   // 80 MB
  _Float16* WT    = (_Float16*)ws;                                    // 128 MB (shared W1T/W2T)

  hipFuncSetAttribute((const void*)k_mm1, hipFuncAttributeMaxDynamicSharedMemorySize, 131072);
  hipFuncSetAttribute((const void*)k_mm2, hipFuncAttributeMaxDynamicSharedMemorySize, 131072);

  hipMemsetAsync(d_out, 0, (size_t)out_size * 4, stream);
  hipMemsetAsync(slot_tok, 0xFF, (size_t)NE * CAP * 4, stream);

  k_router<<<NTOK / 4, 256, 0, stream>>>(x, Wr, probs, P0);
  k_sink<<<32, 256, 0, stream>>>(probs, P0, P1);
  k_sink<<<32, 256, 0, stream>>>(probs, P1, P0);
  k_sink3<<<32, 256, 0, stream>>>(probs, P0, eidx, ew);
  k_scan<<<NE, 256, 0, stream>>>(eidx, ew, slot_tok, slot_w, counts);
  k_aux<<<1, 1, 0, stream>>>(counts, aux);
  k_gather<<<NE * CAP, 256, 0, stream>>>(x, slot_tok, xg);

  dim3 t1(HD / 64, DM / 64, NE);
  k_transpose<<<t1, 256, 0, stream>>>(W1, WT, DM, HD);
  k_mm1<<<768, 512, 131072, stream>>>(xg, WT, b1, hbuf);

  dim3 t2(DM / 64, HD / 64, NE);
  k_transpose<<<t2, 256, 0, stream>>>(W2, WT, HD, DM);
  k_mm2<<<768, 512, 131072, stream>>>(hbuf, WT, b2, slot_tok, slot_w, y);
}

// Round 6
// 572.720 us; speedup vs baseline: 1.0935x; 1.0935x over previous
//
#include <hip/hip_runtime.h>
#include <hip/hip_bf16.h>
#include <math.h>

#define NTOK 8192
#define DM   1024
#define NE   16
#define HD   4096
#define CAP  640

typedef float f32x4 __attribute__((ext_vector_type(4)));
typedef _Float16 f16x8 __attribute__((ext_vector_type(8)));
typedef _Float16 f16x4 __attribute__((ext_vector_type(4)));

__device__ __forceinline__ void gload16(const void* g, void* l) {
  __builtin_amdgcn_global_load_lds(
      (const __attribute__((address_space(1))) unsigned int*)g,
      (__attribute__((address_space(3))) unsigned int*)l, 16, 0, 0);
}

// ---------------- router: logits + softmax + col partials (one wave/token) ----------------
__global__ __launch_bounds__(256) void k_router(const float* __restrict__ x,
                                                const float* __restrict__ Wr,
                                                float* __restrict__ probs,
                                                float* __restrict__ pout) {
  int wave = threadIdx.x >> 6, lane = threadIdx.x & 63;
  int tok = blockIdx.x * 4 + wave;
  const float* xr = x + (size_t)tok * DM;
  float acc[NE];
#pragma unroll
  for (int e = 0; e < NE; ++e) acc[e] = 0.f;
  for (int d = lane; d < DM; d += 64) {
    float xv = xr[d];
    const float* w = Wr + (size_t)d * NE;
#pragma unroll
    for (int e = 0; e < NE; ++e) acc[e] = fmaf(xv, w[e], acc[e]);
  }
#pragma unroll
  for (int off = 32; off >= 1; off >>= 1) {
#pragma unroll
    for (int e = 0; e < NE; ++e) acc[e] += __shfl_xor(acc[e], off, 64);
  }
  float m = acc[0];
#pragma unroll
  for (int e = 1; e < NE; ++e) m = fmaxf(m, acc[e]);
  float s = 0.f;
#pragma unroll
  for (int e = 0; e < NE; ++e) { acc[e] = expf(acc[e] - m); s += acc[e]; }
  float inv = 1.0f / s;
#pragma unroll
  for (int e = 0; e < NE; ++e) acc[e] *= inv;
  if (lane < NE) probs[(size_t)tok * NE + lane] = acc[lane];
  __shared__ float wsum[4][NE];
  if (lane == 0) {
#pragma unroll
    for (int e = 0; e < NE; ++e) wsum[wave][e] = acc[e];
  }
  __syncthreads();
  if (threadIdx.x < NE)
    pout[blockIdx.x * NE + threadIdx.x] =
        wsum[0][threadIdx.x] + wsum[1][threadIdx.x] + wsum[2][threadIdx.x] + wsum[3][threadIdx.x];
}

// ------------- fused sinkhorn step: col-normalize, row-normalize, emit col partials -------------
__global__ __launch_bounds__(256) void k_sink(float* __restrict__ probs,
                                              const float* __restrict__ pin,
                                              float* __restrict__ pout) {
  __shared__ float csinv[NE];
  int tid = threadIdx.x;
  if (tid < NE) {
    float s = 0.f;
#pragma unroll
    for (int b = 0; b < 32; ++b) s += pin[b * NE + tid];
    csinv[tid] = 512.0f / s;
  }
  __syncthreads();
  int tok = blockIdx.x * 256 + tid;
  float* row = probs + (size_t)tok * NE;
  float p[NE]; float rs = 0.f;
#pragma unroll
  for (int e = 0; e < NE; ++e) { p[e] = row[e] * csinv[e]; rs += p[e]; }
  float rinv = 1.0f / rs;
#pragma unroll
  for (int e = 0; e < NE; ++e) { p[e] *= rinv; row[e] = p[e]; }
#pragma unroll
  for (int off = 32; off >= 1; off >>= 1) {
#pragma unroll
    for (int e = 0; e < NE; ++e) p[e] += __shfl_xor(p[e], off, 64);
  }
  __shared__ float wsum[4][NE];
  int lane = tid & 63, wave = tid >> 6;
  if (lane == 0) {
#pragma unroll
    for (int e = 0; e < NE; ++e) wsum[wave][e] = p[e];
  }
  __syncthreads();
  if (tid < NE)
    pout[blockIdx.x * NE + tid] =
        wsum[0][tid] + wsum[1][tid] + wsum[2][tid] + wsum[3][tid];
}

// ------------- final sinkhorn col-normalize fused with top-2 + weight renorm -------------
__global__ __launch_bounds__(256) void k_sink3(const float* __restrict__ probs,
                                               const float* __restrict__ pin,
                                               int* __restrict__ eidx,
                                               float* __restrict__ ew) {
  __shared__ float csinv[NE];
  int tid = threadIdx.x;
  if (tid < NE) {
    float s = 0.f;
#pragma unroll
    for (int b = 0; b < 32; ++b) s += pin[b * NE + tid];
    csinv[tid] = 512.0f / s;
  }
  __syncthreads();
  int tok = blockIdx.x * 256 + tid;
  const float* row = probs + (size_t)tok * NE;
  float v0 = -1e30f, v1 = -1e30f; int e0 = 0, e1 = 0;
#pragma unroll
  for (int e = 0; e < NE; ++e) {
    float v = row[e] * csinv[e];
    if (v > v0) { v1 = v0; e1 = e0; v0 = v; e0 = e; }
    else if (v > v1) { v1 = v; e1 = e; }
  }
  float s = v0 + v1;
  eidx[tok * 2] = e0; eidx[tok * 2 + 1] = e1;
  ew[tok * 2] = v0 / s; ew[tok * 2 + 1] = v1 / s;
}

// ------------- sequential (t,k)-order slot allocation: one block per expert -------------
// Also emits the token-side map tok2slot[i] = e*CAP+pos (or -1 if dropped).
__global__ __launch_bounds__(256) void k_scan(const int* __restrict__ eidx,
                                              int* __restrict__ slot_tok,
                                              int* __restrict__ tok2slot,
                                              int* __restrict__ counts) {
  int e = blockIdx.x;
  int tid = threadIdx.x, lane = tid & 63, wave = tid >> 6;
  __shared__ int wtot[4];
  int running = 0;
  for (int base = 0; base < NTOK * 2; base += 256) {
    int i = base + tid;
    int match = (eidx[i] == e) ? 1 : 0;
    unsigned long long mb = __ballot(match);
    if (lane == 0) wtot[wave] = __popcll(mb);
    __syncthreads();
    int pre = 0;
    for (int w = 0; w < wave; ++w) pre += wtot[w];
    int tot = wtot[0] + wtot[1] + wtot[2] + wtot[3];
    if (match) {
      int pos = running + pre + __popcll(mb & ((1ull << lane) - 1ull));
      if (pos < CAP) {
        slot_tok[e * CAP + pos] = i >> 1;
        tok2slot[i] = e * CAP + pos;
      } else {
        tok2slot[i] = -1;
      }
    }
    running += tot;
    __syncthreads();
  }
  if (tid == 0) counts[e] = running;
}

__global__ void k_aux(const int* __restrict__ counts, float* __restrict__ aux) {
  int s = 0;
#pragma unroll
  for (int e = 0; e < NE; ++e) s += min(counts[e], CAP);
  *aux = 0.01f * (float)s / (float)NTOK;
}

// ------------- gather expert inputs to fp16 (zero-fill unused slots) -------------
__global__ __launch_bounds__(256) void k_gather(const float* __restrict__ x,
                                                const int* __restrict__ slot_tok,
                                                _Float16* __restrict__ xg) {
  int row = blockIdx.x;
  int tok = slot_tok[row];
  int t = threadIdx.x;
  f16x4 h;
  if (tok >= 0) {
    float4 v = *(const float4*)(x + (size_t)tok * DM + t * 4);
    h[0] = (_Float16)v.x; h[1] = (_Float16)v.y; h[2] = (_Float16)v.z; h[3] = (_Float16)v.w;
  } else {
    h[0] = (_Float16)0.f; h[1] = (_Float16)0.f; h[2] = (_Float16)0.f; h[3] = (_Float16)0.f;
  }
  *(f16x4*)(xg + (size_t)row * DM + t * 4) = h;
}

// ------------- transpose+convert: W[e][K][N] fp32 -> WT[e][N][K] fp16 -------------
__global__ __launch_bounds__(256) void k_transpose(const float* __restrict__ W,
                                                   _Float16* __restrict__ WT,
                                                   int K, int N) {
  __shared__ float tile[64][65];
  int e = blockIdx.z;
  int n0 = blockIdx.x * 64, k0 = blockIdx.y * 64;
  const float* src = W + ((size_t)e * K + k0) * N + n0;
  int t = threadIdx.x;
  int kr = t >> 4, nc = (t & 15) * 4;
#pragma unroll
  for (int r = 0; r < 4; ++r) {
    int row = r * 16 + kr;
    float4 v = *(const float4*)(src + (size_t)row * N + nc);
    tile[row][nc + 0] = v.x; tile[row][nc + 1] = v.y;
    tile[row][nc + 2] = v.z; tile[row][nc + 3] = v.w;
  }
  __syncthreads();
  int nr = t >> 3, kc = (t & 7) * 8;
  size_t dstbase = ((size_t)e * N + n0) * (size_t)K + k0;
#pragma unroll
  for (int r = 0; r < 2; ++r) {
    int n = r * 32 + nr;
    f16x8 h;
#pragma unroll
    for (int j = 0; j < 8; ++j) h[j] = (_Float16)tile[kc + j][n];
    *(f16x8*)(WT + dstbase + (size_t)n * K + kc) = h;
  }
}

// ==================== fp16 MFMA GEMMs ====================
// LDS tile layout: [ROWS][64 k] fp16, 16B chunks XOR-swizzled: chunk c stored at c^(row&7).
// global_load_lds writes linearly (lane*16B), so the GLOBAL source address is pre-swizzled.

template<int ROWS>
__device__ __forceinline__ void stage_tile(const _Float16* gbase, int ld, int k0,
                                           _Float16* lds, int w, int lane) {
  constexpr int PER = (ROWS * 8) / 256;   // 16B chunks per thread
#pragma unroll
  for (int i = 0; i < PER; ++i) {
    int ci = (w * PER + i) * 64 + lane;
    int row = ci >> 3, c = ci & 7;
    int cs = c ^ (row & 7);
    gload16(gbase + (size_t)row * ld + k0 + cs * 8, lds + (w * PER + i) * 512);
  }
}

// ---- GEMM1: h = gelu(xg @ W1T^T + b1), 128x128 tile, bounce epilogue ----
__global__ __launch_bounds__(256) void k_gemm1(const _Float16* __restrict__ xg,
                                               const _Float16* __restrict__ W1T,
                                               const float* __restrict__ b1,
                                               _Float16* __restrict__ hbuf) {
  int bid = blockIdx.x;                      // 2560 blocks
  int logical = (bid & 7) * 320 + (bid >> 3);
  int my = logical % 5;
  int nx = (logical / 5) % 32;
  int e  = logical / 160;
  int m0 = my * 128, n0 = nx * 128;
  __shared__ _Float16 smem[2 * 128 * 64];    // As | Bs, reused as 128x128 bounce
  _Float16* As = smem;
  _Float16* Bs = smem + 128 * 64;
  const _Float16* Ab = xg  + ((size_t)e * CAP + m0) * DM;
  const _Float16* Bb = W1T + ((size_t)e * HD  + n0) * DM;
  int tid = threadIdx.x, lane = tid & 63, w = tid >> 6;
  int wr = w >> 1, wc = w & 1;
  int lr = lane & 15, kg = lane >> 4;

  f32x4 zero = {0.f, 0.f, 0.f, 0.f};
  f32x4 acc[4][4];
#pragma unroll
  for (int m = 0; m < 4; ++m)
#pragma unroll
    for (int n = 0; n < 4; ++n) acc[m][n] = zero;

  for (int k0 = 0; k0 < DM; k0 += 64) {
    __syncthreads();
    stage_tile<128>(Ab, DM, k0, As, w, lane);
    stage_tile<128>(Bb, DM, k0, Bs, w, lane);
    __syncthreads();
#pragma unroll
    for (int ks = 0; ks < 2; ++ks) {
      f16x8 af[4], bf[4];
#pragma unroll
      for (int m = 0; m < 4; ++m) {
        int row = wr * 64 + m * 16 + lr;
        int cs = (ks * 4 + kg) ^ (row & 7);
        af[m] = *(const f16x8*)(As + row * 64 + cs * 8);
      }
#pragma unroll
      for (int n = 0; n < 4; ++n) {
        int row = wc * 64 + n * 16 + lr;
        int cs = (ks * 4 + kg) ^ (row & 7);
        bf[n] = *(const f16x8*)(Bs + row * 64 + cs * 8);
      }
#pragma unroll
      for (int m = 0; m < 4; ++m)
#pragma unroll
        for (int n = 0; n < 4; ++n)
          acc[m][n] = __builtin_amdgcn_mfma_f32_16x16x32_f16(af[m], bf[n], acc[m][n], 0, 0, 0);
    }
  }
  // epilogue: bias + exact GELU -> fp16, bounce via LDS for coalesced stores
  __syncthreads();
  _Float16* Cb = smem;   // 128 x 128, col XOR-swizzled by ((row>>2)&3)<<4
  int lq = lane >> 4;
#pragma unroll
  for (int n = 0; n < 4; ++n) {
    int col = wc * 64 + n * 16 + lr;
    float bias = b1[(size_t)e * HD + n0 + col];
#pragma unroll
    for (int m = 0; m < 4; ++m) {
#pragma unroll
      for (int r = 0; r < 4; ++r) {
        int row = wr * 64 + m * 16 + lq * 4 + r;
        float v = acc[m][n][r] + bias;
        v = 0.5f * v * (1.0f + erff(v * 0.70710678118654752f));
        Cb[row * 128 + (col ^ (((row >> 2) & 3) << 4))] = (_Float16)v;
      }
    }
  }
  __syncthreads();
  int rr = tid >> 4;
  int c8 = (tid & 15) * 8;
#pragma unroll
  for (int p = 0; p < 8; ++p) {
    int row = p * 16 + rr;
    int colx = c8 ^ (((row >> 2) & 3) << 4);
    f16x8 v = *(const f16x8*)(Cb + row * 128 + colx);
    *(f16x8*)(hbuf + ((size_t)e * CAP + m0 + row) * HD + n0 + c8) = v;
  }
}

// ---- GEMM2: obuf[e][slot] = h @ W2T^T + b2 (NO atomics), 64x128 tile, 1280 blocks ----
__global__ __launch_bounds__(256) void k_gemm2(const _Float16* __restrict__ hbuf,
                                               const _Float16* __restrict__ W2T,
                                               const float* __restrict__ b2,
                                               _Float16* __restrict__ obuf) {
  int bid = blockIdx.x;                      // 1280 blocks
  int logical = (bid & 7) * 160 + (bid >> 3);
  int my = logical % 10;
  int nx = (logical / 10) % 8;
  int e  = logical / 80;
  int m0 = my * 64, n0 = nx * 128;
  __shared__ _Float16 smem[64 * 64 + 128 * 64];   // As | Bs, reused as 64x128 bounce
  _Float16* As = smem;
  _Float16* Bs = smem + 64 * 64;
  const _Float16* Ab = hbuf + ((size_t)e * CAP + m0) * HD;
  const _Float16* Bb = W2T  + ((size_t)e * DM  + n0) * HD;
  int tid = threadIdx.x, lane = tid & 63, w = tid >> 6;
  int wm = w >> 1, wn = w & 1;
  int lr = lane & 15, kg = lane >> 4;

  f32x4 zero = {0.f, 0.f, 0.f, 0.f};
  f32x4 acc[2][4];
#pragma unroll
  for (int m = 0; m < 2; ++m)
#pragma unroll
    for (int n = 0; n < 4; ++n) acc[m][n] = zero;

  for (int k0 = 0; k0 < HD; k0 += 64) {
    __syncthreads();
    stage_tile<64>(Ab, HD, k0, As, w, lane);
    stage_tile<128>(Bb, HD, k0, Bs, w, lane);
    __syncthreads();
#pragma unroll
    for (int ks = 0; ks < 2; ++ks) {
      f16x8 af[2], bf[4];
#pragma unroll
      for (int m = 0; m < 2; ++m) {
        int row = wm * 32 + m * 16 + lr;
        int cs = (ks * 4 + kg) ^ (row & 7);
        af[m] = *(const f16x8*)(As + row * 64 + cs * 8);
      }
#pragma unroll
      for (int n = 0; n < 4; ++n) {
        int row = wn * 64 + n * 16 + lr;
        int cs = (ks * 4 + kg) ^ (row & 7);
        bf[n] = *(const f16x8*)(Bs + row * 64 + cs * 8);
      }
#pragma unroll
      for (int m = 0; m < 2; ++m)
#pragma unroll
        for (int n = 0; n < 4; ++n)
          acc[m][n] = __builtin_amdgcn_mfma_f32_16x16x32_f16(af[m], bf[n], acc[m][n], 0, 0, 0);
    }
  }
  // epilogue: bias -> fp16 obuf via LDS bounce, fully coalesced, no atomics
  __syncthreads();
  _Float16* Cb = smem;   // 64 x 128, col XOR-swizzled by ((row>>2)&3)<<4
  int lq = lane >> 4;
  float bias[4];
#pragma unroll
  for (int n = 0; n < 4; ++n)
    bias[n] = b2[(size_t)e * DM + n0 + wn * 64 + n * 16 + lr];
#pragma unroll
  for (int m = 0; m < 2; ++m) {
#pragma unroll
    for (int n = 0; n < 4; ++n) {
#pragma unroll
      for (int r = 0; r < 4; ++r) {
        int row = wm * 32 + m * 16 + lq * 4 + r;
        int col = wn * 64 + n * 16 + lr;
        Cb[row * 128 + (col ^ (((row >> 2) & 3) << 4))] = (_Float16)(acc[m][n][r] + bias[n]);
      }
    }
  }
  __syncthreads();
  int rr = tid >> 4;
  int c8 = (tid & 15) * 8;
#pragma unroll
  for (int p = 0; p < 4; ++p) {
    int row = p * 16 + rr;
    int colx = c8 ^ (((row >> 2) & 3) << 4);
    f16x8 v = *(const f16x8*)(Cb + row * 128 + colx);
    *(f16x8*)(obuf + ((size_t)e * CAP + m0 + row) * DM + n0 + c8) = v;
  }
}

// ---- combine: y[t] = sum_k w_k * obuf[slot(t,k)]  (streaming, no atomics) ----
__global__ __launch_bounds__(256) void k_combine(const _Float16* __restrict__ obuf,
                                                 const int* __restrict__ tok2slot,
                                                 const float* __restrict__ ew,
                                                 float* __restrict__ y) {
  int t = blockIdx.x;
  int d = threadIdx.x * 4;
  int i0 = tok2slot[t * 2], i1 = tok2slot[t * 2 + 1];
  float w0 = ew[t * 2], w1 = ew[t * 2 + 1];
  float a0 = 0.f, a1 = 0.f, a2 = 0.f, a3 = 0.f;
  if (i0 >= 0) {
    f16x4 o = *(const f16x4*)(obuf + (size_t)i0 * DM + d);
    a0 += w0 * (float)o[0]; a1 += w0 * (float)o[1];
    a2 += w0 * (float)o[2]; a3 += w0 * (float)o[3];
  }
  if (i1 >= 0) {
    f16x4 o = *(const f16x4*)(obuf + (size_t)i1 * DM + d);
    a0 += w1 * (float)o[0]; a1 += w1 * (float)o[1];
    a2 += w1 * (float)o[2]; a3 += w1 * (float)o[3];
  }
  float4 out = make_float4(a0, a1, a2, a3);
  *(float4*)(y + (size_t)t * DM + d) = out;
}

extern "C" void kernel_launch(void* const* d_in, const int* in_sizes, int n_in,
                              void* d_out, int out_size, void* d_ws, size_t ws_size,
                              hipStream_t stream) {
  const float* x  = (const float*)d_in[0];
  const float* Wr = (const float*)d_in[1];
  const float* W1 = (const float*)d_in[2];
  const float* b1 = (const float*)d_in[3];
  const float* W2 = (const float*)d_in[4];
  const float* b2 = (const float*)d_in[5];
  float* y = (float*)d_out;
  float* aux = y + (size_t)out_size - 1;

  char* ws = (char*)d_ws;
  float* probs    = (float*)ws; ws += (size_t)NTOK * NE * 4;   // 512 KB
  float* P0       = (float*)ws; ws += 32 * NE * 4;
  float* P1       = (float*)ws; ws += 32 * NE * 4;
  int*   eidx     = (int*)ws;   ws += NTOK * 2 * 4;
  float* ew       = (float*)ws; ws += NTOK * 2 * 4;
  int*   slot_tok = (int*)ws;   ws += NE * CAP * 4;
  int*   tok2slot = (int*)ws;   ws += NTOK * 2 * 4;
  int*   counts   = (int*)ws;   ws += 256;
  _Float16* xg    = (_Float16*)ws; ws += (size_t)NE * CAP * DM * 2;   // 20 MB
  _Float16* hbuf  = (_Float16*)ws; ws += (size_t)NE * CAP * HD * 2;   // 80 MB
  _Float16* WT    = (_Float16*)ws;                                    // 128 MB (shared W1T/W2T)
  _Float16* obuf  = xg;   // xg is dead after k_gemm1; obuf is exactly the same size

  hipMemsetAsync(slot_tok, 0xFF, (size_t)NE * CAP * 4, stream);

  k_router<<<NTOK / 4, 256, 0, stream>>>(x, Wr, probs, P0);
  k_sink<<<32, 256, 0, stream>>>(probs, P0, P1);
  k_sink<<<32, 256, 0, stream>>>(probs, P1, P0);
  k_sink3<<<32, 256, 0, stream>>>(probs, P0, eidx, ew);
  k_scan<<<NE, 256, 0, stream>>>(eidx, slot_tok, tok2slot, counts);
  k_aux<<<1, 1, 0, stream>>>(counts, aux);
  k_gather<<<NE * CAP, 256, 0, stream>>>(x, slot_tok, xg);

  dim3 t1(HD / 64, DM / 64, NE);
  k_transpose<<<t1, 256, 0, stream>>>(W1, WT, DM, HD);
  k_gemm1<<<2560, 256, 0, stream>>>(xg, WT, b1, hbuf);

  dim3 t2(DM / 64, HD / 64, NE);
  k_transpose<<<t2, 256, 0, stream>>>(W2, WT, HD, DM);
  k_gemm2<<<1280, 256, 0, stream>>>(hbuf, WT, b2, obuf);

  k_combine<<<NTOK, 256, 0, stream>>>(obuf, tok2slot, ew, y);
}

// Round 7
// 514.535 us; speedup vs baseline: 1.2171x; 1.1131x over previous
//
#include <hip/hip_runtime.h>
#include <hip/hip_bf16.h>
#include <math.h>

#define NTOK 8192
#define DM   1024
#define NE   16
#define HD   4096
#define CAP  640

typedef float f32x4 __attribute__((ext_vector_type(4)));
typedef _Float16 f16x8 __attribute__((ext_vector_type(8)));
typedef _Float16 f16x4 __attribute__((ext_vector_type(4)));

__device__ __forceinline__ void gload16(const void* g, void* l) {
  __builtin_amdgcn_global_load_lds(
      (const __attribute__((address_space(1))) unsigned int*)g,
      (__attribute__((address_space(3))) unsigned int*)l, 16, 0, 0);
}

// fast GELU (tanh form): gelu(v) = v * sigmoid(1.5957691*v + 0.07135481*v^3)
__device__ __forceinline__ float gelu_fast(float v) {
  float v2 = v * v;
  float z2n = v * fmaf(-0.07135481627f, v2, -1.595769122f);   // -2*z
  float e = __expf(z2n);
  return v / (1.0f + e);
}

// ---------------- router: logits + softmax + col partials (one wave/token) ----------------
__global__ __launch_bounds__(256) void k_router(const float* __restrict__ x,
                                                const float* __restrict__ Wr,
                                                float* __restrict__ probs,
                                                float* __restrict__ pout) {
  int wave = threadIdx.x >> 6, lane = threadIdx.x & 63;
  int tok = blockIdx.x * 4 + wave;
  const float* xr = x + (size_t)tok * DM;
  float acc[NE];
#pragma unroll
  for (int e = 0; e < NE; ++e) acc[e] = 0.f;
  for (int d = lane; d < DM; d += 64) {
    float xv = xr[d];
    const float* w = Wr + (size_t)d * NE;
#pragma unroll
    for (int e = 0; e < NE; ++e) acc[e] = fmaf(xv, w[e], acc[e]);
  }
#pragma unroll
  for (int off = 32; off >= 1; off >>= 1) {
#pragma unroll
    for (int e = 0; e < NE; ++e) acc[e] += __shfl_xor(acc[e], off, 64);
  }
  float m = acc[0];
#pragma unroll
  for (int e = 1; e < NE; ++e) m = fmaxf(m, acc[e]);
  float s = 0.f;
#pragma unroll
  for (int e = 0; e < NE; ++e) { acc[e] = expf(acc[e] - m); s += acc[e]; }
  float inv = 1.0f / s;
#pragma unroll
  for (int e = 0; e < NE; ++e) acc[e] *= inv;
  if (lane < NE) probs[(size_t)tok * NE + lane] = acc[lane];
  __shared__ float wsum[4][NE];
  if (lane == 0) {
#pragma unroll
    for (int e = 0; e < NE; ++e) wsum[wave][e] = acc[e];
  }
  __syncthreads();
  if (threadIdx.x < NE)
    pout[blockIdx.x * NE + threadIdx.x] =
        wsum[0][threadIdx.x] + wsum[1][threadIdx.x] + wsum[2][threadIdx.x] + wsum[3][threadIdx.x];
}

// ------------- fused sinkhorn step: col-normalize, row-normalize, emit col partials -------------
__global__ __launch_bounds__(256) void k_sink(float* __restrict__ probs,
                                              const float* __restrict__ pin,
                                              float* __restrict__ pout) {
  __shared__ float csinv[NE];
  int tid = threadIdx.x;
  if (tid < NE) {
    float s = 0.f;
#pragma unroll
    for (int b = 0; b < 32; ++b) s += pin[b * NE + tid];
    csinv[tid] = 512.0f / s;
  }
  __syncthreads();
  int tok = blockIdx.x * 256 + tid;
  float* row = probs + (size_t)tok * NE;
  float p[NE]; float rs = 0.f;
#pragma unroll
  for (int e = 0; e < NE; ++e) { p[e] = row[e] * csinv[e]; rs += p[e]; }
  float rinv = 1.0f / rs;
#pragma unroll
  for (int e = 0; e < NE; ++e) { p[e] *= rinv; row[e] = p[e]; }
#pragma unroll
  for (int off = 32; off >= 1; off >>= 1) {
#pragma unroll
    for (int e = 0; e < NE; ++e) p[e] += __shfl_xor(p[e], off, 64);
  }
  __shared__ float wsum[4][NE];
  int lane = tid & 63, wave = tid >> 6;
  if (lane == 0) {
#pragma unroll
    for (int e = 0; e < NE; ++e) wsum[wave][e] = p[e];
  }
  __syncthreads();
  if (tid < NE)
    pout[blockIdx.x * NE + tid] =
        wsum[0][tid] + wsum[1][tid] + wsum[2][tid] + wsum[3][tid];
}

// ------------- final sinkhorn col-normalize fused with top-2 + weight renorm -------------
__global__ __launch_bounds__(256) void k_sink3(const float* __restrict__ probs,
                                               const float* __restrict__ pin,
                                               int* __restrict__ eidx,
                                               float* __restrict__ ew) {
  __shared__ float csinv[NE];
  int tid = threadIdx.x;
  if (tid < NE) {
    float s = 0.f;
#pragma unroll
    for (int b = 0; b < 32; ++b) s += pin[b * NE + tid];
    csinv[tid] = 512.0f / s;
  }
  __syncthreads();
  int tok = blockIdx.x * 256 + tid;
  const float* row = probs + (size_t)tok * NE;
  float v0 = -1e30f, v1 = -1e30f; int e0 = 0, e1 = 0;
#pragma unroll
  for (int e = 0; e < NE; ++e) {
    float v = row[e] * csinv[e];
    if (v > v0) { v1 = v0; e1 = e0; v0 = v; e0 = e; }
    else if (v > v1) { v1 = v; e1 = e; }
  }
  float s = v0 + v1;
  eidx[tok * 2] = e0; eidx[tok * 2 + 1] = e1;
  ew[tok * 2] = v0 / s; ew[tok * 2 + 1] = v1 / s;
}

// ------------- sequential (t,k)-order slot allocation: one block per expert -------------
__global__ __launch_bounds__(256) void k_scan(const int* __restrict__ eidx,
                                              int* __restrict__ slot_tok,
                                              int* __restrict__ tok2slot,
                                              int* __restrict__ counts) {
  int e = blockIdx.x;
  int tid = threadIdx.x, lane = tid & 63, wave = tid >> 6;
  __shared__ int wtot[4];
  int running = 0;
  for (int base = 0; base < NTOK * 2; base += 256) {
    int i = base + tid;
    int match = (eidx[i] == e) ? 1 : 0;
    unsigned long long mb = __ballot(match);
    if (lane == 0) wtot[wave] = __popcll(mb);
    __syncthreads();
    int pre = 0;
    for (int w = 0; w < wave; ++w) pre += wtot[w];
    int tot = wtot[0] + wtot[1] + wtot[2] + wtot[3];
    if (match) {
      int pos = running + pre + __popcll(mb & ((1ull << lane) - 1ull));
      if (pos < CAP) {
        slot_tok[e * CAP + pos] = i >> 1;
        tok2slot[i] = e * CAP + pos;
      } else {
        tok2slot[i] = -1;
      }
    }
    running += tot;
    __syncthreads();
  }
  if (tid == 0) counts[e] = running;
}

__global__ void k_aux(const int* __restrict__ counts, float* __restrict__ aux) {
  int s = 0;
#pragma unroll
  for (int e = 0; e < NE; ++e) s += min(counts[e], CAP);
  *aux = 0.01f * (float)s / (float)NTOK;
}

// ------------- gather expert inputs to fp16 (zero-fill unused slots) -------------
__global__ __launch_bounds__(256) void k_gather(const float* __restrict__ x,
                                                const int* __restrict__ slot_tok,
                                                _Float16* __restrict__ xg) {
  int row = blockIdx.x;
  int tok = slot_tok[row];
  int t = threadIdx.x;
  f16x4 h;
  if (tok >= 0) {
    float4 v = *(const float4*)(x + (size_t)tok * DM + t * 4);
    h[0] = (_Float16)v.x; h[1] = (_Float16)v.y; h[2] = (_Float16)v.z; h[3] = (_Float16)v.w;
  } else {
    h[0] = (_Float16)0.f; h[1] = (_Float16)0.f; h[2] = (_Float16)0.f; h[3] = (_Float16)0.f;
  }
  *(f16x4*)(xg + (size_t)row * DM + t * 4) = h;
}

// ==================== fp16 MFMA GEMMs, B staged from fp32 W with fused transpose ====================
// A-LDS: [ROWS][64k] fp16, 16B chunks XOR-swizzled (c ^= row&7), filled by global_load_lds with
//        pre-swizzled per-lane global source (writes linear).
// B-LDS: [128n][64k] fp16, 16B chunk at position kc ^ ((n^(n>>2))&7), filled by reg-staging:
//        each thread loads 8 fp32 rows (float4) of W[k][n], converts, writes 4 ds_write_b128.

template<int ROWS>
__device__ __forceinline__ void stage_tileA(const _Float16* gbase, int ld, int k0,
                                            _Float16* lds, int w, int lane) {
  constexpr int PER = (ROWS * 8) / 256;   // 16B chunks per thread
#pragma unroll
  for (int i = 0; i < PER; ++i) {
    int ci = (w * PER + i) * 64 + lane;
    int row = ci >> 3, c = ci & 7;
    int cs = c ^ (row & 7);
    gload16(gbase + (size_t)row * ld + k0 + cs * 8, lds + (w * PER + i) * 512);
  }
}

// load 8 float4 rows of the fp32 B-tile: thread (nq=tid&31, kc=tid>>5) covers cols nq*4..+3, k kc*8..+7
__device__ __forceinline__ void loadB8(const float* gb, int ld, int k0, int tid, float4* L) {
  int nq = tid & 31, kc = tid >> 5;
  const float* p = gb + (size_t)(k0 + kc * 8) * ld + nq * 4;
#pragma unroll
  for (int j = 0; j < 8; ++j) L[j] = *(const float4*)(p + (size_t)j * ld);
}

__device__ __forceinline__ void writeB(_Float16* Bs, int tid, const float4* L) {
  int nq = tid & 31, kc = tid >> 5;
#pragma unroll
  for (int i = 0; i < 4; ++i) {
    int n = nq * 4 + i;
    int pos = kc ^ ((n ^ (n >> 2)) & 7);
    f16x8 v;
#pragma unroll
    for (int j = 0; j < 8; ++j) {
      float f = (i == 0) ? L[j].x : (i == 1) ? L[j].y : (i == 2) ? L[j].z : L[j].w;
      v[j] = (_Float16)f;
    }
    *(f16x8*)(Bs + n * 64 + pos * 8) = v;
  }
}

// ---- GEMM1: h = gelu(xg @ W1 + b1), 128x128 tile, 2560 blocks ----
__global__ __launch_bounds__(256) void k_gemm1(const _Float16* __restrict__ xg,
                                               const float* __restrict__ W1,
                                               const float* __restrict__ b1,
                                               _Float16* __restrict__ hbuf) {
  int bid = blockIdx.x;
  int logical = (bid & 7) * 320 + (bid >> 3);
  int my = logical % 5;
  int nx = (logical / 5) % 32;
  int e  = logical / 160;
  int m0 = my * 128, n0 = nx * 128;
  __shared__ _Float16 smem[2 * 128 * 64];    // As | Bs, reused as 128x128 bounce
  _Float16* As = smem;
  _Float16* Bs = smem + 128 * 64;
  const _Float16* Ab = xg + ((size_t)e * CAP + m0) * DM;
  const float*    Bb = W1 + (size_t)e * DM * HD + n0;     // ld = HD
  int tid = threadIdx.x, lane = tid & 63, w = tid >> 6;
  int wr = w >> 1, wc = w & 1;
  int lr = lane & 15, kg = lane >> 4;

  f32x4 zero = {0.f, 0.f, 0.f, 0.f};
  f32x4 acc[4][4];
#pragma unroll
  for (int m = 0; m < 4; ++m)
#pragma unroll
    for (int n = 0; n < 4; ++n) acc[m][n] = zero;

  float4 L[8];
  loadB8(Bb, HD, 0, tid, L);
  for (int t = 0; t < 16; ++t) {
    __syncthreads();
    stage_tileA<128>(Ab, DM, t * 64, As, w, lane);
    writeB(Bs, tid, L);
    __syncthreads();
    if (t + 1 < 16) loadB8(Bb, HD, (t + 1) * 64, tid, L);
#pragma unroll
    for (int ks = 0; ks < 2; ++ks) {
      f16x8 af[4], bf[4];
#pragma unroll
      for (int m = 0; m < 4; ++m) {
        int row = wr * 64 + m * 16 + lr;
        int cs = (ks * 4 + kg) ^ (row & 7);
        af[m] = *(const f16x8*)(As + row * 64 + cs * 8);
      }
#pragma unroll
      for (int n = 0; n < 4; ++n) {
        int row = wc * 64 + n * 16 + lr;
        int cs = (ks * 4 + kg) ^ ((row ^ (row >> 2)) & 7);
        bf[n] = *(const f16x8*)(Bs + row * 64 + cs * 8);
      }
#pragma unroll
      for (int m = 0; m < 4; ++m)
#pragma unroll
        for (int n = 0; n < 4; ++n)
          acc[m][n] = __builtin_amdgcn_mfma_f32_16x16x32_f16(af[m], bf[n], acc[m][n], 0, 0, 0);
    }
  }
  // epilogue: bias + fast GELU -> fp16, bounce via LDS for coalesced stores
  __syncthreads();
  _Float16* Cb = smem;   // 128 x 128, col XOR-swizzled by ((row>>2)&3)<<4
  int lq = lane >> 4;
#pragma unroll
  for (int n = 0; n < 4; ++n) {
    int col = wc * 64 + n * 16 + lr;
    float bias = b1[(size_t)e * HD + n0 + col];
#pragma unroll
    for (int m = 0; m < 4; ++m) {
#pragma unroll
      for (int r = 0; r < 4; ++r) {
        int row = wr * 64 + m * 16 + lq * 4 + r;
        float v = gelu_fast(acc[m][n][r] + bias);
        Cb[row * 128 + (col ^ (((row >> 2) & 3) << 4))] = (_Float16)v;
      }
    }
  }
  __syncthreads();
  int rr = tid >> 4;
  int c8 = (tid & 15) * 8;
#pragma unroll
  for (int p = 0; p < 8; ++p) {
    int row = p * 16 + rr;
    int colx = c8 ^ (((row >> 2) & 3) << 4);
    f16x8 v = *(const f16x8*)(Cb + row * 128 + colx);
    *(f16x8*)(hbuf + ((size_t)e * CAP + m0 + row) * HD + n0 + c8) = v;
  }
}

// ---- GEMM2: obuf[e][slot] = h @ W2 + b2 (no atomics), 64x128 tile, 1280 blocks ----
__global__ __launch_bounds__(256) void k_gemm2(const _Float16* __restrict__ hbuf,
                                               const float* __restrict__ W2,
                                               const float* __restrict__ b2,
                                               _Float16* __restrict__ obuf) {
  int bid = blockIdx.x;
  int logical = (bid & 7) * 160 + (bid >> 3);
  int my = logical % 10;
  int nx = (logical / 10) % 8;
  int e  = logical / 80;
  int m0 = my * 64, n0 = nx * 128;
  __shared__ _Float16 smem[64 * 64 + 128 * 64];   // As | Bs, reused as 64x128 bounce
  _Float16* As = smem;
  _Float16* Bs = smem + 64 * 64;
  const _Float16* Ab = hbuf + ((size_t)e * CAP + m0) * HD;
  const float*    Bb = W2 + (size_t)e * HD * DM + n0;     // ld = DM
  int tid = threadIdx.x, lane = tid & 63, w = tid >> 6;
  int wm = w >> 1, wn = w & 1;
  int lr = lane & 15, kg = lane >> 4;

  f32x4 zero = {0.f, 0.f, 0.f, 0.f};
  f32x4 acc[2][4];
#pragma unroll
  for (int m = 0; m < 2; ++m)
#pragma unroll
    for (int n = 0; n < 4; ++n) acc[m][n] = zero;

  float4 L[8];
  loadB8(Bb, DM, 0, tid, L);
  for (int t = 0; t < 64; ++t) {
    __syncthreads();
    stage_tileA<64>(Ab, HD, t * 64, As, w, lane);
    writeB(Bs, tid, L);
    __syncthreads();
    if (t + 1 < 64) loadB8(Bb, DM, (t + 1) * 64, tid, L);
#pragma unroll
    for (int ks = 0; ks < 2; ++ks) {
      f16x8 af[2], bf[4];
#pragma unroll
      for (int m = 0; m < 2; ++m) {
        int row = wm * 32 + m * 16 + lr;
        int cs = (ks * 4 + kg) ^ (row & 7);
        af[m] = *(const f16x8*)(As + row * 64 + cs * 8);
      }
#pragma unroll
      for (int n = 0; n < 4; ++n) {
        int row = wn * 64 + n * 16 + lr;
        int cs = (ks * 4 + kg) ^ ((row ^ (row >> 2)) & 7);
        bf[n] = *(const f16x8*)(Bs + row * 64 + cs * 8);
      }
#pragma unroll
      for (int m = 0; m < 2; ++m)
#pragma unroll
        for (int n = 0; n < 4; ++n)
          acc[m][n] = __builtin_amdgcn_mfma_f32_16x16x32_f16(af[m], bf[n], acc[m][n], 0, 0, 0);
    }
  }
  // epilogue: bias -> fp16 obuf via LDS bounce, fully coalesced
  __syncthreads();
  _Float16* Cb = smem;   // 64 x 128, col XOR-swizzled by ((row>>2)&3)<<4
  int lq = lane >> 4;
  float bias[4];
#pragma unroll
  for (int n = 0; n < 4; ++n)
    bias[n] = b2[(size_t)e * DM + n0 + wn * 64 + n * 16 + lr];
#pragma unroll
  for (int m = 0; m < 2; ++m) {
#pragma unroll
    for (int n = 0; n < 4; ++n) {
#pragma unroll
      for (int r = 0; r < 4; ++r) {
        int row = wm * 32 + m * 16 + lq * 4 + r;
        int col = wn * 64 + n * 16 + lr;
        Cb[row * 128 + (col ^ (((row >> 2) & 3) << 4))] = (_Float16)(acc[m][n][r] + bias[n]);
      }
    }
  }
  __syncthreads();
  int rr = tid >> 4;
  int c8 = (tid & 15) * 8;
#pragma unroll
  for (int p = 0; p < 4; ++p) {
    int row = p * 16 + rr;
    int colx = c8 ^ (((row >> 2) & 3) << 4);
    f16x8 v = *(const f16x8*)(Cb + row * 128 + colx);
    *(f16x8*)(obuf + ((size_t)e * CAP + m0 + row) * DM + n0 + c8) = v;
  }
}

// ---- combine: y[t] = sum_k w_k * obuf[slot(t,k)]  (streaming, no atomics) ----
__global__ __launch_bounds__(256) void k_combine(const _Float16* __restrict__ obuf,
                                                 const int* __restrict__ tok2slot,
                                                 const float* __restrict__ ew,
                                                 float* __restrict__ y) {
  int t = blockIdx.x;
  int d = threadIdx.x * 4;
  int i0 = tok2slot[t * 2], i1 = tok2slot[t * 2 + 1];
  float w0 = ew[t * 2], w1 = ew[t * 2 + 1];
  float a0 = 0.f, a1 = 0.f, a2 = 0.f, a3 = 0.f;
  if (i0 >= 0) {
    f16x4 o = *(const f16x4*)(obuf + (size_t)i0 * DM + d);
    a0 += w0 * (float)o[0]; a1 += w0 * (float)o[1];
    a2 += w0 * (float)o[2]; a3 += w0 * (float)o[3];
  }
  if (i1 >= 0) {
    f16x4 o = *(const f16x4*)(obuf + (size_t)i1 * DM + d);
    a0 += w1 * (float)o[0]; a1 += w1 * (float)o[1];
    a2 += w1 * (float)o[2]; a3 += w1 * (float)o[3];
  }
  float4 out = make_float4(a0, a1, a2, a3);
  *(float4*)(y + (size_t)t * DM + d) = out;
}

extern "C" void kernel_launch(void* const* d_in, const int* in_sizes, int n_in,
                              void* d_out, int out_size, void* d_ws, size_t ws_size,
                              hipStream_t stream) {
  const float* x  = (const float*)d_in[0];
  const float* Wr = (const float*)d_in[1];
  const float* W1 = (const float*)d_in[2];
  const float* b1 = (const float*)d_in[3];
  const float* W2 = (const float*)d_in[4];
  const float* b2 = (const float*)d_in[5];
  float* y = (float*)d_out;
  float* aux = y + (size_t)out_size - 1;

  char* ws = (char*)d_ws;
  float* probs    = (float*)ws; ws += (size_t)NTOK * NE * 4;   // 512 KB
  float* P0       = (float*)ws; ws += 32 * NE * 4;
  float* P1       = (float*)ws; ws += 32 * NE * 4;
  int*   eidx     = (int*)ws;   ws += NTOK * 2 * 4;
  float* ew       = (float*)ws; ws += NTOK * 2 * 4;
  int*   slot_tok = (int*)ws;   ws += NE * CAP * 4;
  int*   tok2slot = (int*)ws;   ws += NTOK * 2 * 4;
  int*   counts   = (int*)ws;   ws += 256;
  _Float16* xg    = (_Float16*)ws; ws += (size_t)NE * CAP * DM * 2;   // 20 MB
  _Float16* hbuf  = (_Float16*)ws; ws += (size_t)NE * CAP * HD * 2;   // 80 MB
  _Float16* obuf  = xg;   // xg is dead after k_gemm1; obuf is the same size

  hipMemsetAsync(slot_tok, 0xFF, (size_t)NE * CAP * 4, stream);

  k_router<<<NTOK / 4, 256, 0, stream>>>(x, Wr, probs, P0);
  k_sink<<<32, 256, 0, stream>>>(probs, P0, P1);
  k_sink<<<32, 256, 0, stream>>>(probs, P1, P0);
  k_sink3<<<32, 256, 0, stream>>>(probs, P0, eidx, ew);
  k_scan<<<NE, 256, 0, stream>>>(eidx, slot_tok, tok2slot, counts);
  k_aux<<<1, 1, 0, stream>>>(counts, aux);
  k_gather<<<NE * CAP, 256, 0, stream>>>(x, slot_tok, xg);

  k_gemm1<<<2560, 256, 0, stream>>>(xg, W1, b1, hbuf);
  k_gemm2<<<1280, 256, 0, stream>>>(hbuf, W2, b2, obuf);

  k_combine<<<NTOK, 256, 0, stream>>>(obuf, tok2slot, ew, y);
}

// Round 8
// 461.247 us; speedup vs baseline: 1.3577x; 1.1155x over previous
//
#include <hip/hip_runtime.h>
#include <hip/hip_bf16.h>
#include <math.h>

#define NTOK 8192
#define DM   1024
#define NE   16
#define HD   4096
#define CAP  640
#define NCHUNK 64   // (NTOK*2)/256

typedef float f32x4 __attribute__((ext_vector_type(4)));
typedef _Float16 f16x8 __attribute__((ext_vector_type(8)));
typedef _Float16 f16x4 __attribute__((ext_vector_type(4)));

__device__ __forceinline__ void gload16(const void* g, void* l) {
  __builtin_amdgcn_global_load_lds(
      (const __attribute__((address_space(1))) unsigned int*)g,
      (__attribute__((address_space(3))) unsigned int*)l, 16, 0, 0);
}

// fast GELU (tanh form)
__device__ __forceinline__ float gelu_fast(float v) {
  float v2 = v * v;
  float z2n = v * fmaf(-0.07135481627f, v2, -1.595769122f);
  float e = __expf(z2n);
  return v / (1.0f + e);
}

// ---------------- router: logits + softmax + col partials (one wave/token) ----------------
__global__ __launch_bounds__(256) void k_router(const float* __restrict__ x,
                                                const float* __restrict__ Wr,
                                                float* __restrict__ probs,
                                                float* __restrict__ pout) {
  int wave = threadIdx.x >> 6, lane = threadIdx.x & 63;
  int tok = blockIdx.x * 4 + wave;
  const float* xr = x + (size_t)tok * DM;
  float acc[NE];
#pragma unroll
  for (int e = 0; e < NE; ++e) acc[e] = 0.f;
  for (int d = lane; d < DM; d += 64) {
    float xv = xr[d];
    const float* w = Wr + (size_t)d * NE;
#pragma unroll
    for (int e = 0; e < NE; ++e) acc[e] = fmaf(xv, w[e], acc[e]);
  }
#pragma unroll
  for (int off = 32; off >= 1; off >>= 1) {
#pragma unroll
    for (int e = 0; e < NE; ++e) acc[e] += __shfl_xor(acc[e], off, 64);
  }
  float m = acc[0];
#pragma unroll
  for (int e = 1; e < NE; ++e) m = fmaxf(m, acc[e]);
  float s = 0.f;
#pragma unroll
  for (int e = 0; e < NE; ++e) { acc[e] = expf(acc[e] - m); s += acc[e]; }
  float inv = 1.0f / s;
#pragma unroll
  for (int e = 0; e < NE; ++e) acc[e] *= inv;
  if (lane < NE) probs[(size_t)tok * NE + lane] = acc[lane];
  __shared__ float wsum[4][NE];
  if (lane == 0) {
#pragma unroll
    for (int e = 0; e < NE; ++e) wsum[wave][e] = acc[e];
  }
  __syncthreads();
  if (threadIdx.x < NE)
    pout[blockIdx.x * NE + threadIdx.x] =
        wsum[0][threadIdx.x] + wsum[1][threadIdx.x] + wsum[2][threadIdx.x] + wsum[3][threadIdx.x];
}

// ------------- fused sinkhorn step -------------
__global__ __launch_bounds__(256) void k_sink(float* __restrict__ probs,
                                              const float* __restrict__ pin,
                                              float* __restrict__ pout) {
  __shared__ float csinv[NE];
  int tid = threadIdx.x;
  if (tid < NE) {
    float s = 0.f;
#pragma unroll
    for (int b = 0; b < 32; ++b) s += pin[b * NE + tid];
    csinv[tid] = 512.0f / s;
  }
  __syncthreads();
  int tok = blockIdx.x * 256 + tid;
  float* row = probs + (size_t)tok * NE;
  float p[NE]; float rs = 0.f;
#pragma unroll
  for (int e = 0; e < NE; ++e) { p[e] = row[e] * csinv[e]; rs += p[e]; }
  float rinv = 1.0f / rs;
#pragma unroll
  for (int e = 0; e < NE; ++e) { p[e] *= rinv; row[e] = p[e]; }
#pragma unroll
  for (int off = 32; off >= 1; off >>= 1) {
#pragma unroll
    for (int e = 0; e < NE; ++e) p[e] += __shfl_xor(p[e], off, 64);
  }
  __shared__ float wsum[4][NE];
  int lane = tid & 63, wave = tid >> 6;
  if (lane == 0) {
#pragma unroll
    for (int e = 0; e < NE; ++e) wsum[wave][e] = p[e];
  }
  __syncthreads();
  if (tid < NE)
    pout[blockIdx.x * NE + tid] =
        wsum[0][tid] + wsum[1][tid] + wsum[2][tid] + wsum[3][tid];
}

// ------------- final col-normalize + top-2 + renorm -------------
__global__ __launch_bounds__(256) void k_sink3(const float* __restrict__ probs,
                                               const float* __restrict__ pin,
                                               int* __restrict__ eidx,
                                               float* __restrict__ ew) {
  __shared__ float csinv[NE];
  int tid = threadIdx.x;
  if (tid < NE) {
    float s = 0.f;
#pragma unroll
    for (int b = 0; b < 32; ++b) s += pin[b * NE + tid];
    csinv[tid] = 512.0f / s;
  }
  __syncthreads();
  int tok = blockIdx.x * 256 + tid;
  const float* row = probs + (size_t)tok * NE;
  float v0 = -1e30f, v1 = -1e30f; int e0 = 0, e1 = 0;
#pragma unroll
  for (int e = 0; e < NE; ++e) {
    float v = row[e] * csinv[e];
    if (v > v0) { v1 = v0; e1 = e0; v0 = v; e0 = e; }
    else if (v > v1) { v1 = v; e1 = e; }
  }
  float s = v0 + v1;
  eidx[tok * 2] = e0; eidx[tok * 2 + 1] = e1;
  ew[tok * 2] = v0 / s; ew[tok * 2 + 1] = v1 / s;
}

// ------------- parallel slot allocation (3 kernels, (t,k) order preserved) -------------
// kA: per-chunk expert histogram
__global__ __launch_bounds__(256) void k_hist(const int* __restrict__ eidx,
                                              int* __restrict__ cnt) {
  __shared__ int h[NE];
  int tid = threadIdx.x, c = blockIdx.x;
  if (tid < NE) h[tid] = 0;
  __syncthreads();
  atomicAdd(&h[eidx[c * 256 + tid]], 1);
  __syncthreads();
  if (tid < NE) cnt[c * NE + tid] = h[tid];
}

// kB: per-expert exclusive prefix over chunks + aux loss
__global__ __launch_bounds__(64) void k_prefix(const int* __restrict__ cnt,
                                               int* __restrict__ base,
                                               int* __restrict__ counts,
                                               float* __restrict__ aux) {
  __shared__ int tot[NE];
  int e = threadIdx.x;
  if (e < NE) {
    int run = 0;
    for (int c = 0; c < NCHUNK; ++c) {
      base[c * NE + e] = run;
      run += cnt[c * NE + e];
    }
    counts[e] = run;
    tot[e] = min(run, CAP);
  }
  __syncthreads();
  if (e == 0) {
    int s = 0;
#pragma unroll
    for (int i = 0; i < NE; ++i) s += tot[i];
    *aux = 0.01f * (float)s / (float)NTOK;
  }
}

// kC: assign positions = chunk base + intra-chunk rank (per-wave ballots)
__global__ __launch_bounds__(256) void k_assign(const int* __restrict__ eidx,
                                                const int* __restrict__ base,
                                                int* __restrict__ slot_tok,
                                                int* __restrict__ tok2slot) {
  __shared__ int wcnt[4][NE];
  __shared__ int cbase[NE];
  int tid = threadIdx.x, c = blockIdx.x, lane = tid & 63, wave = tid >> 6;
  int i = c * 256 + tid;
  int myE = eidx[i];
  if (tid < NE) cbase[tid] = base[c * NE + tid];
  int mypre = 0;
#pragma unroll
  for (int e = 0; e < NE; ++e) {
    unsigned long long m = __ballot(myE == e);
    if (myE == e) mypre = __popcll(m & ((1ull << lane) - 1ull));
    if (lane == 0) wcnt[wave][e] = __popcll(m);
  }
  __syncthreads();
  int pre = 0;
  for (int w = 0; w < wave; ++w) pre += wcnt[w][myE];
  int pos = cbase[myE] + pre + mypre;
  if (pos < CAP) {
    slot_tok[myE * CAP + pos] = i >> 1;
    tok2slot[i] = myE * CAP + pos;
  } else {
    tok2slot[i] = -1;
  }
}

// ------------- gather expert inputs to fp16 (zero-fill unused slots) -------------
__global__ __launch_bounds__(256) void k_gather(const float* __restrict__ x,
                                                const int* __restrict__ slot_tok,
                                                _Float16* __restrict__ xg) {
  int row = blockIdx.x;
  int tok = slot_tok[row];
  int t = threadIdx.x;
  f16x4 h;
  if (tok >= 0) {
    float4 v = *(const float4*)(x + (size_t)tok * DM + t * 4);
    h[0] = (_Float16)v.x; h[1] = (_Float16)v.y; h[2] = (_Float16)v.z; h[3] = (_Float16)v.w;
  } else {
    h[0] = (_Float16)0.f; h[1] = (_Float16)0.f; h[2] = (_Float16)0.f; h[3] = (_Float16)0.f;
  }
  *(f16x4*)(xg + (size_t)row * DM + t * 4) = h;
}

// ==================== fp16 MFMA GEMMs, B staged from fp32 W with fused transpose ====================
template<int ROWS>
__device__ __forceinline__ void stage_tileA(const _Float16* gbase, int ld, int k0,
                                            _Float16* lds, int w, int lane) {
  constexpr int PER = (ROWS * 8) / 256;
#pragma unroll
  for (int i = 0; i < PER; ++i) {
    int ci = (w * PER + i) * 64 + lane;
    int row = ci >> 3, c = ci & 7;
    int cs = c ^ (row & 7);
    gload16(gbase + (size_t)row * ld + k0 + cs * 8, lds + (w * PER + i) * 512);
  }
}

__device__ __forceinline__ void loadB8(const float* gb, int ld, int k0, int tid, float4* L) {
  int nq = tid & 31, kc = tid >> 5;
  const float* p = gb + (size_t)(k0 + kc * 8) * ld + nq * 4;
#pragma unroll
  for (int j = 0; j < 8; ++j) L[j] = *(const float4*)(p + (size_t)j * ld);
}

__device__ __forceinline__ void writeB(_Float16* Bs, int tid, const float4* L) {
  int nq = tid & 31, kc = tid >> 5;
#pragma unroll
  for (int i = 0; i < 4; ++i) {
    int n = nq * 4 + i;
    int pos = kc ^ ((n ^ (n >> 2)) & 7);
    f16x8 v;
#pragma unroll
    for (int j = 0; j < 8; ++j) {
      float f = (i == 0) ? L[j].x : (i == 1) ? L[j].y : (i == 2) ? L[j].z : L[j].w;
      v[j] = (_Float16)f;
    }
    *(f16x8*)(Bs + n * 64 + pos * 8) = v;
  }
}

// ---- GEMM1: h = gelu(xg @ W1 + b1), 128x128 tile, 2560 blocks ----
__global__ __launch_bounds__(256) void k_gemm1(const _Float16* __restrict__ xg,
                                               const float* __restrict__ W1,
                                               const float* __restrict__ b1,
                                               _Float16* __restrict__ hbuf) {
  int bid = blockIdx.x;
  int logical = (bid & 7) * 320 + (bid >> 3);
  int my = logical % 5;
  int nx = (logical / 5) % 32;
  int e  = logical / 160;
  int m0 = my * 128, n0 = nx * 128;
  __shared__ _Float16 smem[2 * 128 * 64];
  _Float16* As = smem;
  _Float16* Bs = smem + 128 * 64;
  const _Float16* Ab = xg + ((size_t)e * CAP + m0) * DM;
  const float*    Bb = W1 + (size_t)e * DM * HD + n0;     // ld = HD
  int tid = threadIdx.x, lane = tid & 63, w = tid >> 6;
  int wr = w >> 1, wc = w & 1;
  int lr = lane & 15, kg = lane >> 4;

  f32x4 zero = {0.f, 0.f, 0.f, 0.f};
  f32x4 acc[4][4];
#pragma unroll
  for (int m = 0; m < 4; ++m)
#pragma unroll
    for (int n = 0; n < 4; ++n) acc[m][n] = zero;

  float4 L[8];
  loadB8(Bb, HD, 0, tid, L);
  for (int t = 0; t < 16; ++t) {
    __syncthreads();
    stage_tileA<128>(Ab, DM, t * 64, As, w, lane);
    writeB(Bs, tid, L);
    __syncthreads();
    if (t + 1 < 16) loadB8(Bb, HD, (t + 1) * 64, tid, L);
#pragma unroll
    for (int ks = 0; ks < 2; ++ks) {
      f16x8 af[4], bf[4];
#pragma unroll
      for (int m = 0; m < 4; ++m) {
        int row = wr * 64 + m * 16 + lr;
        int cs = (ks * 4 + kg) ^ (row & 7);
        af[m] = *(const f16x8*)(As + row * 64 + cs * 8);
      }
#pragma unroll
      for (int n = 0; n < 4; ++n) {
        int row = wc * 64 + n * 16 + lr;
        int cs = (ks * 4 + kg) ^ ((row ^ (row >> 2)) & 7);
        bf[n] = *(const f16x8*)(Bs + row * 64 + cs * 8);
      }
#pragma unroll
      for (int m = 0; m < 4; ++m)
#pragma unroll
        for (int n = 0; n < 4; ++n)
          acc[m][n] = __builtin_amdgcn_mfma_f32_16x16x32_f16(af[m], bf[n], acc[m][n], 0, 0, 0);
    }
  }
  __syncthreads();
  _Float16* Cb = smem;
  int lq = lane >> 4;
#pragma unroll
  for (int n = 0; n < 4; ++n) {
    int col = wc * 64 + n * 16 + lr;
    float bias = b1[(size_t)e * HD + n0 + col];
#pragma unroll
    for (int m = 0; m < 4; ++m) {
#pragma unroll
      for (int r = 0; r < 4; ++r) {
        int row = wr * 64 + m * 16 + lq * 4 + r;
        float v = gelu_fast(acc[m][n][r] + bias);
        Cb[row * 128 + (col ^ (((row >> 2) & 3) << 4))] = (_Float16)v;
      }
    }
  }
  __syncthreads();
  int rr = tid >> 4;
  int c8 = (tid & 15) * 8;
#pragma unroll
  for (int p = 0; p < 8; ++p) {
    int row = p * 16 + rr;
    int colx = c8 ^ (((row >> 2) & 3) << 4);
    f16x8 v = *(const f16x8*)(Cb + row * 128 + colx);
    *(f16x8*)(hbuf + ((size_t)e * CAP + m0 + row) * HD + n0 + c8) = v;
  }
}

// ---- GEMM2: Pks[e][slot] = h @ W2[kslice] (+b2 on ks==0), 128x128 tile, K-split 2, 1280 blocks ----
__global__ __launch_bounds__(256) void k_gemm2(const _Float16* __restrict__ hbuf,
                                               const float* __restrict__ W2,
                                               const float* __restrict__ b2,
                                               _Float16* __restrict__ P0,
                                               _Float16* __restrict__ P1) {
  int bid = blockIdx.x;
  int logical = (bid & 7) * 160 + (bid >> 3);
  int my = logical % 5;
  int nx = (logical / 5) % 8;
  int ks2 = (logical / 40) & 1;
  int e  = logical / 80;
  int m0 = my * 128, n0 = nx * 128, kbase = ks2 * 2048;
  __shared__ _Float16 smem[2 * 128 * 64];
  _Float16* As = smem;
  _Float16* Bs = smem + 128 * 64;
  const _Float16* Ab = hbuf + ((size_t)e * CAP + m0) * HD;
  const float*    Bb = W2 + (size_t)e * HD * DM + n0;     // ld = DM
  int tid = threadIdx.x, lane = tid & 63, w = tid >> 6;
  int wr = w >> 1, wc = w & 1;
  int lr = lane & 15, kg = lane >> 4;

  f32x4 zero = {0.f, 0.f, 0.f, 0.f};
  f32x4 acc[4][4];
#pragma unroll
  for (int m = 0; m < 4; ++m)
#pragma unroll
    for (int n = 0; n < 4; ++n) acc[m][n] = zero;

  float4 L[8];
  loadB8(Bb, DM, kbase, tid, L);
  for (int t = 0; t < 32; ++t) {
    __syncthreads();
    stage_tileA<128>(Ab, HD, kbase + t * 64, As, w, lane);
    writeB(Bs, tid, L);
    __syncthreads();
    if (t + 1 < 32) loadB8(Bb, DM, kbase + (t + 1) * 64, tid, L);
#pragma unroll
    for (int ks = 0; ks < 2; ++ks) {
      f16x8 af[4], bf[4];
#pragma unroll
      for (int m = 0; m < 4; ++m) {
        int row = wr * 64 + m * 16 + lr;
        int cs = (ks * 4 + kg) ^ (row & 7);
        af[m] = *(const f16x8*)(As + row * 64 + cs * 8);
      }
#pragma unroll
      for (int n = 0; n < 4; ++n) {
        int row = wc * 64 + n * 16 + lr;
        int cs = (ks * 4 + kg) ^ ((row ^ (row >> 2)) & 7);
        bf[n] = *(const f16x8*)(Bs + row * 64 + cs * 8);
      }
#pragma unroll
      for (int m = 0; m < 4; ++m)
#pragma unroll
        for (int n = 0; n < 4; ++n)
          acc[m][n] = __builtin_amdgcn_mfma_f32_16x16x32_f16(af[m], bf[n], acc[m][n], 0, 0, 0);
    }
  }
  // epilogue: (+bias on ks==0) -> fp16 partial via LDS bounce
  __syncthreads();
  _Float16* Cb = smem;
  _Float16* P = (ks2 == 0) ? P0 : P1;
  int lq = lane >> 4;
  float bias[4];
#pragma unroll
  for (int n = 0; n < 4; ++n)
    bias[n] = (ks2 == 0) ? b2[(size_t)e * DM + n0 + wc * 64 + n * 16 + lr] : 0.f;
#pragma unroll
  for (int m = 0; m < 4; ++m) {
#pragma unroll
    for (int n = 0; n < 4; ++n) {
#pragma unroll
      for (int r = 0; r < 4; ++r) {
        int row = wr * 64 + m * 16 + lq * 4 + r;
        int col = wc * 64 + n * 16 + lr;
        Cb[row * 128 + (col ^ (((row >> 2) & 3) << 4))] = (_Float16)(acc[m][n][r] + bias[n]);
      }
    }
  }
  __syncthreads();
  int rr = tid >> 4;
  int c8 = (tid & 15) * 8;
#pragma unroll
  for (int p = 0; p < 8; ++p) {
    int row = p * 16 + rr;
    int colx = c8 ^ (((row >> 2) & 3) << 4);
    f16x8 v = *(const f16x8*)(Cb + row * 128 + colx);
    *(f16x8*)(P + ((size_t)e * CAP + m0 + row) * DM + n0 + c8) = v;
  }
}

// ---- combine: y[t] = sum_k w_k * (P0[slot]+P1[slot]) ----
__global__ __launch_bounds__(256) void k_combine(const _Float16* __restrict__ P0,
                                                 const _Float16* __restrict__ P1,
                                                 const int* __restrict__ tok2slot,
                                                 const float* __restrict__ ew,
                                                 float* __restrict__ y) {
  int t = blockIdx.x;
  int d = threadIdx.x * 4;
  int i0 = tok2slot[t * 2], i1 = tok2slot[t * 2 + 1];
  float w0 = ew[t * 2], w1 = ew[t * 2 + 1];
  float a0 = 0.f, a1 = 0.f, a2 = 0.f, a3 = 0.f;
  if (i0 >= 0) {
    f16x4 oa = *(const f16x4*)(P0 + (size_t)i0 * DM + d);
    f16x4 ob = *(const f16x4*)(P1 + (size_t)i0 * DM + d);
    a0 += w0 * ((float)oa[0] + (float)ob[0]); a1 += w0 * ((float)oa[1] + (float)ob[1]);
    a2 += w0 * ((float)oa[2] + (float)ob[2]); a3 += w0 * ((float)oa[3] + (float)ob[3]);
  }
  if (i1 >= 0) {
    f16x4 oa = *(const f16x4*)(P0 + (size_t)i1 * DM + d);
    f16x4 ob = *(const f16x4*)(P1 + (size_t)i1 * DM + d);
    a0 += w1 * ((float)oa[0] + (float)ob[0]); a1 += w1 * ((float)oa[1] + (float)ob[1]);
    a2 += w1 * ((float)oa[2] + (float)ob[2]); a3 += w1 * ((float)oa[3] + (float)ob[3]);
  }
  float4 out = make_float4(a0, a1, a2, a3);
  *(float4*)(y + (size_t)t * DM + d) = out;
}

extern "C" void kernel_launch(void* const* d_in, const int* in_sizes, int n_in,
                              void* d_out, int out_size, void* d_ws, size_t ws_size,
                              hipStream_t stream) {
  const float* x  = (const float*)d_in[0];
  const float* Wr = (const float*)d_in[1];
  const float* W1 = (const float*)d_in[2];
  const float* b1 = (const float*)d_in[3];
  const float* W2 = (const float*)d_in[4];
  const float* b2 = (const float*)d_in[5];
  float* y = (float*)d_out;
  float* aux = y + (size_t)out_size - 1;

  char* ws = (char*)d_ws;
  float* probs    = (float*)ws; ws += (size_t)NTOK * NE * 4;   // 512 KB
  float* C0       = (float*)ws; ws += 32 * NE * 4;
  float* C1       = (float*)ws; ws += 32 * NE * 4;
  int*   eidx     = (int*)ws;   ws += NTOK * 2 * 4;
  float* ew       = (float*)ws; ws += NTOK * 2 * 4;
  int*   slot_tok = (int*)ws;   ws += NE * CAP * 4;
  int*   tok2slot = (int*)ws;   ws += NTOK * 2 * 4;
  int*   counts   = (int*)ws;   ws += 256;
  int*   cnt      = (int*)ws;   ws += NCHUNK * NE * 4;
  int*   cbase    = (int*)ws;   ws += NCHUNK * NE * 4;
  _Float16* xg    = (_Float16*)ws; ws += (size_t)NE * CAP * DM * 2;   // 20 MB
  _Float16* hbuf  = (_Float16*)ws; ws += (size_t)NE * CAP * HD * 2;   // 80 MB
  _Float16* P1b   = (_Float16*)ws; ws += (size_t)NE * CAP * DM * 2;   // 20 MB
  _Float16* P0b   = xg;   // xg dead after k_gemm1

  hipMemsetAsync(slot_tok, 0xFF, (size_t)NE * CAP * 4, stream);

  k_router<<<NTOK / 4, 256, 0, stream>>>(x, Wr, probs, C0);
  k_sink<<<32, 256, 0, stream>>>(probs, C0, C1);
  k_sink<<<32, 256, 0, stream>>>(probs, C1, C0);
  k_sink3<<<32, 256, 0, stream>>>(probs, C0, eidx, ew);
  k_hist<<<NCHUNK, 256, 0, stream>>>(eidx, cnt);
  k_prefix<<<1, 64, 0, stream>>>(cnt, cbase, counts, aux);
  k_assign<<<NCHUNK, 256, 0, stream>>>(eidx, cbase, slot_tok, tok2slot);
  k_gather<<<NE * CAP, 256, 0, stream>>>(x, slot_tok, xg);

  k_gemm1<<<2560, 256, 0, stream>>>(xg, W1, b1, hbuf);
  k_gemm2<<<1280, 256, 0, stream>>>(hbuf, W2, b2, P0b, P1b);

  k_combine<<<NTOK, 256, 0, stream>>>(P0b, P1b, tok2slot, ew, y);
}

// Round 9
// 384.394 us; speedup vs baseline: 1.6292x; 1.1999x over previous
//
#include <hip/hip_runtime.h>
#include <hip/hip_bf16.h>
#include <math.h>

#define NTOK 8192
#define DM   1024
#define NE   16
#define HD   4096
#define CAP  640
#define NCHUNK 64   // (NTOK*2)/256

typedef float f32x4 __attribute__((ext_vector_type(4)));
typedef _Float16 f16x8 __attribute__((ext_vector_type(8)));
typedef _Float16 f16x4 __attribute__((ext_vector_type(4)));

__device__ __forceinline__ void gload16(const void* g, void* l) {
  __builtin_amdgcn_global_load_lds(
      (const __attribute__((address_space(1))) unsigned int*)g,
      (__attribute__((address_space(3))) unsigned int*)l, 16, 0, 0);
}

// fast GELU (tanh form)
__device__ __forceinline__ float gelu_fast(float v) {
  float v2 = v * v;
  float z2n = v * fmaf(-0.07135481627f, v2, -1.595769122f);
  float e = __expf(z2n);
  return v / (1.0f + e);
}

// ---------------- router: logits + softmax + col partials (one wave/token) ----------------
__global__ __launch_bounds__(256) void k_router(const float* __restrict__ x,
                                                const float* __restrict__ Wr,
                                                float* __restrict__ probs,
                                                float* __restrict__ pout) {
  int wave = threadIdx.x >> 6, lane = threadIdx.x & 63;
  int tok = blockIdx.x * 4 + wave;
  const float* xr = x + (size_t)tok * DM;
  float acc[NE];
#pragma unroll
  for (int e = 0; e < NE; ++e) acc[e] = 0.f;
  for (int d = lane; d < DM; d += 64) {
    float xv = xr[d];
    const float* w = Wr + (size_t)d * NE;
#pragma unroll
    for (int e = 0; e < NE; ++e) acc[e] = fmaf(xv, w[e], acc[e]);
  }
#pragma unroll
  for (int off = 32; off >= 1; off >>= 1) {
#pragma unroll
    for (int e = 0; e < NE; ++e) acc[e] += __shfl_xor(acc[e], off, 64);
  }
  float m = acc[0];
#pragma unroll
  for (int e = 1; e < NE; ++e) m = fmaxf(m, acc[e]);
  float s = 0.f;
#pragma unroll
  for (int e = 0; e < NE; ++e) { acc[e] = expf(acc[e] - m); s += acc[e]; }
  float inv = 1.0f / s;
#pragma unroll
  for (int e = 0; e < NE; ++e) acc[e] *= inv;
  if (lane < NE) probs[(size_t)tok * NE + lane] = acc[lane];
  __shared__ float wsum[4][NE];
  if (lane == 0) {
#pragma unroll
    for (int e = 0; e < NE; ++e) wsum[wave][e] = acc[e];
  }
  __syncthreads();
  if (threadIdx.x < NE)
    pout[blockIdx.x * NE + threadIdx.x] =
        wsum[0][threadIdx.x] + wsum[1][threadIdx.x] + wsum[2][threadIdx.x] + wsum[3][threadIdx.x];
}

// ------------- fused sinkhorn step -------------
__global__ __launch_bounds__(256) void k_sink(float* __restrict__ probs,
                                              const float* __restrict__ pin,
                                              float* __restrict__ pout) {
  __shared__ float csinv[NE];
  int tid = threadIdx.x;
  if (tid < NE) {
    float s = 0.f;
#pragma unroll
    for (int b = 0; b < 32; ++b) s += pin[b * NE + tid];
    csinv[tid] = 512.0f / s;
  }
  __syncthreads();
  int tok = blockIdx.x * 256 + tid;
  float* row = probs + (size_t)tok * NE;
  float p[NE]; float rs = 0.f;
#pragma unroll
  for (int e = 0; e < NE; ++e) { p[e] = row[e] * csinv[e]; rs += p[e]; }
  float rinv = 1.0f / rs;
#pragma unroll
  for (int e = 0; e < NE; ++e) { p[e] *= rinv; row[e] = p[e]; }
#pragma unroll
  for (int off = 32; off >= 1; off >>= 1) {
#pragma unroll
    for (int e = 0; e < NE; ++e) p[e] += __shfl_xor(p[e], off, 64);
  }
  __shared__ float wsum[4][NE];
  int lane = tid & 63, wave = tid >> 6;
  if (lane == 0) {
#pragma unroll
    for (int e = 0; e < NE; ++e) wsum[wave][e] = p[e];
  }
  __syncthreads();
  if (tid < NE)
    pout[blockIdx.x * NE + tid] =
        wsum[0][tid] + wsum[1][tid] + wsum[2][tid] + wsum[3][tid];
}

// ------------- final col-normalize + top-2 + renorm -------------
__global__ __launch_bounds__(256) void k_sink3(const float* __restrict__ probs,
                                               const float* __restrict__ pin,
                                               int* __restrict__ eidx,
                                               float* __restrict__ ew) {
  __shared__ float csinv[NE];
  int tid = threadIdx.x;
  if (tid < NE) {
    float s = 0.f;
#pragma unroll
    for (int b = 0; b < 32; ++b) s += pin[b * NE + tid];
    csinv[tid] = 512.0f / s;
  }
  __syncthreads();
  int tok = blockIdx.x * 256 + tid;
  const float* row = probs + (size_t)tok * NE;
  float v0 = -1e30f, v1 = -1e30f; int e0 = 0, e1 = 0;
#pragma unroll
  for (int e = 0; e < NE; ++e) {
    float v = row[e] * csinv[e];
    if (v > v0) { v1 = v0; e1 = e0; v0 = v; e0 = e; }
    else if (v > v1) { v1 = v; e1 = e; }
  }
  float s = v0 + v1;
  eidx[tok * 2] = e0; eidx[tok * 2 + 1] = e1;
  ew[tok * 2] = v0 / s; ew[tok * 2 + 1] = v1 / s;
}

// ------------- parallel slot allocation (3 kernels, (t,k) order preserved) -------------
__global__ __launch_bounds__(256) void k_hist(const int* __restrict__ eidx,
                                              int* __restrict__ cnt) {
  __shared__ int h[NE];
  int tid = threadIdx.x, c = blockIdx.x;
  if (tid < NE) h[tid] = 0;
  __syncthreads();
  atomicAdd(&h[eidx[c * 256 + tid]], 1);
  __syncthreads();
  if (tid < NE) cnt[c * NE + tid] = h[tid];
}

__global__ __launch_bounds__(64) void k_prefix(const int* __restrict__ cnt,
                                               int* __restrict__ base,
                                               int* __restrict__ counts,
                                               float* __restrict__ aux) {
  __shared__ int tot[NE];
  int e = threadIdx.x;
  if (e < NE) {
    int run = 0;
    for (int c = 0; c < NCHUNK; ++c) {
      base[c * NE + e] = run;
      run += cnt[c * NE + e];
    }
    counts[e] = run;
    tot[e] = min(run, CAP);
  }
  __syncthreads();
  if (e == 0) {
    int s = 0;
#pragma unroll
    for (int i = 0; i < NE; ++i) s += tot[i];
    *aux = 0.01f * (float)s / (float)NTOK;
  }
}

__global__ __launch_bounds__(256) void k_assign(const int* __restrict__ eidx,
                                                const int* __restrict__ base,
                                                int* __restrict__ slot_tok,
                                                int* __restrict__ tok2slot) {
  __shared__ int wcnt[4][NE];
  __shared__ int cbase[NE];
  int tid = threadIdx.x, c = blockIdx.x, lane = tid & 63, wave = tid >> 6;
  int i = c * 256 + tid;
  int myE = eidx[i];
  if (tid < NE) cbase[tid] = base[c * NE + tid];
  int mypre = 0;
#pragma unroll
  for (int e = 0; e < NE; ++e) {
    unsigned long long m = __ballot(myE == e);
    if (myE == e) mypre = __popcll(m & ((1ull << lane) - 1ull));
    if (lane == 0) wcnt[wave][e] = __popcll(m);
  }
  __syncthreads();
  int pre = 0;
  for (int w = 0; w < wave; ++w) pre += wcnt[w][myE];
  int pos = cbase[myE] + pre + mypre;
  if (pos < CAP) {
    slot_tok[myE * CAP + pos] = i >> 1;
    tok2slot[i] = myE * CAP + pos;
  } else {
    tok2slot[i] = -1;
  }
}

// ------------- gather expert inputs to fp16 (zero-fill unused slots) -------------
__global__ __launch_bounds__(256) void k_gather(const float* __restrict__ x,
                                                const int* __restrict__ slot_tok,
                                                _Float16* __restrict__ xg) {
  int row = blockIdx.x;
  int tok = slot_tok[row];
  int t = threadIdx.x;
  f16x4 h;
  if (tok >= 0) {
    float4 v = *(const float4*)(x + (size_t)tok * DM + t * 4);
    h[0] = (_Float16)v.x; h[1] = (_Float16)v.y; h[2] = (_Float16)v.z; h[3] = (_Float16)v.w;
  } else {
    h[0] = (_Float16)0.f; h[1] = (_Float16)0.f; h[2] = (_Float16)0.f; h[3] = (_Float16)0.f;
  }
  *(f16x4*)(xg + (size_t)row * DM + t * 4) = h;
}

// ==================== fp16 MFMA GEMMs, async A-dbuf + counted vmcnt ====================
// A-LDS: double-buffered [128][64k] fp16 (16 KB each), 16B chunks XOR-swizzled (c ^= row&7),
//        filled by global_load_lds (pre-swizzled global source, linear LDS dest).
// B-LDS: [128n][64k] fp16, chunk pos = kc ^ ((n^(n>>2))&7), reg-staged from fp32 W (fused
//        transpose+convert). B prefetch (8 float4) issued one k-step early.
// Loop: raw s_barrier + counted vmcnt(8) at step end (A(t+1)'s 4 gload16 drained, 8 B-loads
//       stay in flight) — A staging latency hides under the MFMA phase.

__device__ __forceinline__ void stage_tileA128(const _Float16* gbase, int ld, int k0,
                                               _Float16* lds, int w, int lane) {
#pragma unroll
  for (int i = 0; i < 4; ++i) {
    int ci = (w * 4 + i) * 64 + lane;
    int row = ci >> 3, c = ci & 7;
    int cs = c ^ (row & 7);
    gload16(gbase + (size_t)row * ld + k0 + cs * 8, lds + (w * 4 + i) * 512);
  }
}

__device__ __forceinline__ void loadB8(const float* gb, int ld, int k0, int tid, float4* L) {
  int nq = tid & 31, kc = tid >> 5;
  const float* p = gb + (size_t)(k0 + kc * 8) * ld + nq * 4;
#pragma unroll
  for (int j = 0; j < 8; ++j) L[j] = *(const float4*)(p + (size_t)j * ld);
}

__device__ __forceinline__ void writeB(_Float16* Bs, int tid, const float4* L) {
  int nq = tid & 31, kc = tid >> 5;
#pragma unroll
  for (int i = 0; i < 4; ++i) {
    int n = nq * 4 + i;
    int pos = kc ^ ((n ^ (n >> 2)) & 7);
    f16x8 v;
#pragma unroll
    for (int j = 0; j < 8; ++j) {
      float f = (i == 0) ? L[j].x : (i == 1) ? L[j].y : (i == 2) ? L[j].z : L[j].w;
      v[j] = (_Float16)f;
    }
    *(f16x8*)(Bs + n * 64 + pos * 8) = v;
  }
}

#define MFMA_PHASE(Ac, Bs)                                                         \
  _Pragma("unroll")                                                                \
  for (int ks = 0; ks < 2; ++ks) {                                                 \
    f16x8 af[4], bf[4];                                                            \
    _Pragma("unroll")                                                              \
    for (int m = 0; m < 4; ++m) {                                                  \
      int row = wr * 64 + m * 16 + lr;                                             \
      int cs = (ks * 4 + kg) ^ (row & 7);                                          \
      af[m] = *(const f16x8*)((Ac) + row * 64 + cs * 8);                           \
    }                                                                              \
    _Pragma("unroll")                                                              \
    for (int n = 0; n < 4; ++n) {                                                  \
      int row = wc * 64 + n * 16 + lr;                                             \
      int cs = (ks * 4 + kg) ^ ((row ^ (row >> 2)) & 7);                           \
      bf[n] = *(const f16x8*)((Bs) + row * 64 + cs * 8);                           \
    }                                                                              \
    __builtin_amdgcn_s_setprio(1);                                                 \
    _Pragma("unroll")                                                              \
    for (int m = 0; m < 4; ++m)                                                    \
      _Pragma("unroll")                                                            \
      for (int n = 0; n < 4; ++n)                                                  \
        acc[m][n] = __builtin_amdgcn_mfma_f32_16x16x32_f16(af[m], bf[n], acc[m][n], 0, 0, 0); \
    __builtin_amdgcn_s_setprio(0);                                                 \
  }

#define ASYNC_K_LOOP(NT, AB, ALD, BB, BLD, KBASE)                                  \
  {                                                                                \
    stage_tileA128((AB), (ALD), (KBASE), As0, w, lane);                            \
    loadB8((BB), (BLD), (KBASE), tid, L);                                          \
    asm volatile("s_waitcnt vmcnt(0)" ::: "memory");                               \
    __builtin_amdgcn_s_barrier();                                                  \
    __builtin_amdgcn_sched_barrier(0);                                             \
    for (int t = 0; t < (NT); ++t) {                                               \
      const _Float16* Ac = (t & 1) ? As1 : As0;                                    \
      _Float16* An = (t & 1) ? As0 : As1;                                          \
      writeB(Bs, tid, L);                                                          \
      if (t + 1 < (NT)) {                                                          \
        stage_tileA128((AB), (ALD), (KBASE) + (t + 1) * 64, An, w, lane);          \
        loadB8((BB), (BLD), (KBASE) + (t + 1) * 64, tid, L);                       \
      }                                                                            \
      asm volatile("s_waitcnt lgkmcnt(0)" ::: "memory");                           \
      __builtin_amdgcn_s_barrier();                                                \
      __builtin_amdgcn_sched_barrier(0);                                           \
      MFMA_PHASE(Ac, Bs);                                                          \
      __builtin_amdgcn_sched_barrier(0);                                           \
      if (t + 1 < (NT)) { asm volatile("s_waitcnt vmcnt(8)" ::: "memory"); }       \
      else              { asm volatile("s_waitcnt vmcnt(0)" ::: "memory"); }       \
      __builtin_amdgcn_s_barrier();                                                \
      __builtin_amdgcn_sched_barrier(0);                                           \
    }                                                                              \
  }

// ---- GEMM1: h = gelu(xg @ W1 + b1), 128x128 tile, 2560 blocks ----
__global__ __launch_bounds__(256) void k_gemm1(const _Float16* __restrict__ xg,
                                               const float* __restrict__ W1,
                                               const float* __restrict__ b1,
                                               _Float16* __restrict__ hbuf) {
  int bid = blockIdx.x;
  int logical = (bid & 7) * 320 + (bid >> 3);
  int my = logical % 5;
  int nx = (logical / 5) % 32;
  int e  = logical / 160;
  int m0 = my * 128, n0 = nx * 128;
  __shared__ _Float16 smem[3 * 128 * 64];     // As0 | As1 | Bs ; first 32 KB reused as bounce
  _Float16* As0 = smem;
  _Float16* As1 = smem + 8192;
  _Float16* Bs  = smem + 16384;
  const _Float16* Ab = xg + ((size_t)e * CAP + m0) * DM;
  const float*    Bb = W1 + (size_t)e * DM * HD + n0;     // ld = HD
  int tid = threadIdx.x, lane = tid & 63, w = tid >> 6;
  int wr = w >> 1, wc = w & 1;
  int lr = lane & 15, kg = lane >> 4;

  f32x4 acc[4][4];
#pragma unroll
  for (int m = 0; m < 4; ++m)
#pragma unroll
    for (int n = 0; n < 4; ++n) acc[m][n] = (f32x4){0.f, 0.f, 0.f, 0.f};

  float4 L[8];
  ASYNC_K_LOOP(16, Ab, DM, Bb, HD, 0);

  // epilogue: bias + fast GELU -> fp16, bounce via LDS for coalesced stores
  __syncthreads();
  _Float16* Cb = smem;
  int lq = lane >> 4;
#pragma unroll
  for (int n = 0; n < 4; ++n) {
    int col = wc * 64 + n * 16 + lr;
    float bias = b1[(size_t)e * HD + n0 + col];
#pragma unroll
    for (int m = 0; m < 4; ++m) {
#pragma unroll
      for (int r = 0; r < 4; ++r) {
        int row = wr * 64 + m * 16 + lq * 4 + r;
        float v = gelu_fast(acc[m][n][r] + bias);
        Cb[row * 128 + (col ^ (((row >> 2) & 3) << 4))] = (_Float16)v;
      }
    }
  }
  __syncthreads();
  int rr = tid >> 4;
  int c8 = (tid & 15) * 8;
#pragma unroll
  for (int p = 0; p < 8; ++p) {
    int row = p * 16 + rr;
    int colx = c8 ^ (((row >> 2) & 3) << 4);
    f16x8 v = *(const f16x8*)(Cb + row * 128 + colx);
    *(f16x8*)(hbuf + ((size_t)e * CAP + m0 + row) * HD + n0 + c8) = v;
  }
}

// ---- GEMM2: Pks[e][slot] = h @ W2[kslice] (+b2 on ks==0), 128x128 tile, K-split 2, 1280 blocks ----
__global__ __launch_bounds__(256) void k_gemm2(const _Float16* __restrict__ hbuf,
                                               const float* __restrict__ W2,
                                               const float* __restrict__ b2,
                                               _Float16* __restrict__ P0,
                                               _Float16* __restrict__ P1) {
  int bid = blockIdx.x;
  int logical = (bid & 7) * 160 + (bid >> 3);
  int my = logical % 5;
  int nx = (logical / 5) % 8;
  int ks2 = (logical / 40) & 1;
  int e  = logical / 80;
  int m0 = my * 128, n0 = nx * 128, kbase = ks2 * 2048;
  __shared__ _Float16 smem[3 * 128 * 64];
  _Float16* As0 = smem;
  _Float16* As1 = smem + 8192;
  _Float16* Bs  = smem + 16384;
  const _Float16* Ab = hbuf + ((size_t)e * CAP + m0) * HD;
  const float*    Bb = W2 + (size_t)e * HD * DM + n0;     // ld = DM
  int tid = threadIdx.x, lane = tid & 63, w = tid >> 6;
  int wr = w >> 1, wc = w & 1;
  int lr = lane & 15, kg = lane >> 4;

  f32x4 acc[4][4];
#pragma unroll
  for (int m = 0; m < 4; ++m)
#pragma unroll
    for (int n = 0; n < 4; ++n) acc[m][n] = (f32x4){0.f, 0.f, 0.f, 0.f};

  float4 L[8];
  ASYNC_K_LOOP(32, Ab, HD, Bb, DM, kbase);

  // epilogue: (+bias on ks==0) -> fp16 partial via LDS bounce
  __syncthreads();
  _Float16* Cb = smem;
  _Float16* P = (ks2 == 0) ? P0 : P1;
  int lq = lane >> 4;
  float bias[4];
#pragma unroll
  for (int n = 0; n < 4; ++n)
    bias[n] = (ks2 == 0) ? b2[(size_t)e * DM + n0 + wc * 64 + n * 16 + lr] : 0.f;
#pragma unroll
  for (int m = 0; m < 4; ++m) {
#pragma unroll
    for (int n = 0; n < 4; ++n) {
#pragma unroll
      for (int r = 0; r < 4; ++r) {
        int row = wr * 64 + m * 16 + lq * 4 + r;
        int col = wc * 64 + n * 16 + lr;
        Cb[row * 128 + (col ^ (((row >> 2) & 3) << 4))] = (_Float16)(acc[m][n][r] + bias[n]);
      }
    }
  }
  __syncthreads();
  int rr = tid >> 4;
  int c8 = (tid & 15) * 8;
#pragma unroll
  for (int p = 0; p < 8; ++p) {
    int row = p * 16 + rr;
    int colx = c8 ^ (((row >> 2) & 3) << 4);
    f16x8 v = *(const f16x8*)(Cb + row * 128 + colx);
    *(f16x8*)(P + ((size_t)e * CAP + m0 + row) * DM + n0 + c8) = v;
  }
}

// ---- combine: y[t] = sum_k w_k * (P0[slot]+P1[slot]) ----
__global__ __launch_bounds__(256) void k_combine(const _Float16* __restrict__ P0,
                                                 const _Float16* __restrict__ P1,
                                                 const int* __restrict__ tok2slot,
                                                 const float* __restrict__ ew,
                                                 float* __restrict__ y) {
  int t = blockIdx.x;
  int d = threadIdx.x * 4;
  int i0 = tok2slot[t * 2], i1 = tok2slot[t * 2 + 1];
  float w0 = ew[t * 2], w1 = ew[t * 2 + 1];
  float a0 = 0.f, a1 = 0.f, a2 = 0.f, a3 = 0.f;
  if (i0 >= 0) {
    f16x4 oa = *(const f16x4*)(P0 + (size_t)i0 * DM + d);
    f16x4 ob = *(const f16x4*)(P1 + (size_t)i0 * DM + d);
    a0 += w0 * ((float)oa[0] + (float)ob[0]); a1 += w0 * ((float)oa[1] + (float)ob[1]);
    a2 += w0 * ((float)oa[2] + (float)ob[2]); a3 += w0 * ((float)oa[3] + (float)ob[3]);
  }
  if (i1 >= 0) {
    f16x4 oa = *(const f16x4*)(P0 + (size_t)i1 * DM + d);
    f16x4 ob = *(const f16x4*)(P1 + (size_t)i1 * DM + d);
    a0 += w1 * ((float)oa[0] + (float)ob[0]); a1 += w1 * ((float)oa[1] + (float)ob[1]);
    a2 += w1 * ((float)oa[2] + (float)ob[2]); a3 += w1 * ((float)oa[3] + (float)ob[3]);
  }
  float4 out = make_float4(a0, a1, a2, a3);
  *(float4*)(y + (size_t)t * DM + d) = out;
}

extern "C" void kernel_launch(void* const* d_in, const int* in_sizes, int n_in,
                              void* d_out, int out_size, void* d_ws, size_t ws_size,
                              hipStream_t stream) {
  const float* x  = (const float*)d_in[0];
  const float* Wr = (const float*)d_in[1];
  const float* W1 = (const float*)d_in[2];
  const float* b1 = (const float*)d_in[3];
  const float* W2 = (const float*)d_in[4];
  const float* b2 = (const float*)d_in[5];
  float* y = (float*)d_out;
  float* aux = y + (size_t)out_size - 1;

  char* ws = (char*)d_ws;
  float* probs    = (float*)ws; ws += (size_t)NTOK * NE * 4;   // 512 KB
  float* C0       = (float*)ws; ws += 32 * NE * 4;
  float* C1       = (float*)ws; ws += 32 * NE * 4;
  int*   eidx     = (int*)ws;   ws += NTOK * 2 * 4;
  float* ew       = (float*)ws; ws += NTOK * 2 * 4;
  int*   slot_tok = (int*)ws;   ws += NE * CAP * 4;
  int*   tok2slot = (int*)ws;   ws += NTOK * 2 * 4;
  int*   counts   = (int*)ws;   ws += 256;
  int*   cnt      = (int*)ws;   ws += NCHUNK * NE * 4;
  int*   cbase    = (int*)ws;   ws += NCHUNK * NE * 4;
  _Float16* xg    = (_Float16*)ws; ws += (size_t)NE * CAP * DM * 2;   // 20 MB
  _Float16* hbuf  = (_Float16*)ws; ws += (size_t)NE * CAP * HD * 2;   // 80 MB
  _Float16* P1b   = (_Float16*)ws; ws += (size_t)NE * CAP * DM * 2;   // 20 MB
  _Float16* P0b   = xg;   // xg dead after k_gemm1

  hipMemsetAsync(slot_tok, 0xFF, (size_t)NE * CAP * 4, stream);

  k_router<<<NTOK / 4, 256, 0, stream>>>(x, Wr, probs, C0);
  k_sink<<<32, 256, 0, stream>>>(probs, C0, C1);
  k_sink<<<32, 256, 0, stream>>>(probs, C1, C0);
  k_sink3<<<32, 256, 0, stream>>>(probs, C0, eidx, ew);
  k_hist<<<NCHUNK, 256, 0, stream>>>(eidx, cnt);
  k_prefix<<<1, 64, 0, stream>>>(cnt, cbase, counts, aux);
  k_assign<<<NCHUNK, 256, 0, stream>>>(eidx, cbase, slot_tok, tok2slot);
  k_gather<<<NE * CAP, 256, 0, stream>>>(x, slot_tok, xg);

  k_gemm1<<<2560, 256, 0, stream>>>(xg, W1, b1, hbuf);
  k_gemm2<<<1280, 256, 0, stream>>>(hbuf, W2, b2, P0b, P1b);

  k_combine<<<NTOK, 256, 0, stream>>>(P0b, P1b, tok2slot, ew, y);
}